// Round 17
// baseline (240.149 us; speedup 1.0000x reference)
//
#include <hip/hip_runtime.h>

#define N_TOK 49152
#define PER_E 155648      // expert blob: 19 stages * 8192 bf16 elems per expert
#define NSTAGE 19
#define RSTAGES 24        // router blob: 24 stages * 8192 bf16 elems
#define MAXTILES 774

// d_out float offsets
#define TRAJ_OFF 0
#define SCORE_OFF 5898240
#define AUX_OFF  5947392
#define PROB_OFF 5947393

typedef __attribute__((ext_vector_type(8))) short short8v;
typedef __attribute__((ext_vector_type(4))) float f32x4;
typedef __attribute__((ext_vector_type(4))) unsigned short u16x4;

typedef __attribute__((address_space(3))) unsigned char lds_byte;
typedef __attribute__((address_space(1))) const unsigned char gl_byte;

__device__ __forceinline__ unsigned short f2bf(float f) {
  unsigned int u = __float_as_uint(f);
  u = (u + 0x7FFFu + ((u >> 16) & 1u)) >> 16;
  return (unsigned short)u;
}
__device__ __forceinline__ float bf2f(unsigned short h) {
  return __uint_as_float(((unsigned int)h) << 16);
}
// pack two f32 -> 2x bf16 in one instruction
__device__ __forceinline__ unsigned int pkbf(float a, float b) {
  unsigned int r;
  asm("v_cvt_pk_bf16_f32 %0, %1, %2" : "=v"(r) : "v"(a), "v"(b));
  return r;
}
// precise erf-gelu (A&S 7.1.26, err <1.5e-7) -- ROUTER ONLY (top-2 flip safety)
__device__ __forceinline__ float geluf(float v) {
  float x = v * 0.70710678118654752f;
  float ax = fabsf(x);
  float t = __builtin_amdgcn_rcpf(fmaf(0.3275911f, ax, 1.0f));
  float p = t * fmaf(t, fmaf(t, fmaf(t, fmaf(t, 1.061405429f, -1.453152027f),
                                     1.421413741f), -0.284496736f), 0.254829592f);
  float er = 1.0f - p * __expf(-ax * ax);
  er = copysignf(er, x);
  return 0.5f * v * (1.0f + er);
}
// fast erf-gelu (A&S 7.1.25, err <2.5e-5) -- expert path
__device__ __forceinline__ float geluf_fast(float v) {
  float x = v * 0.70710678f;
  float ax = fabsf(x);
  float t = __builtin_amdgcn_rcpf(fmaf(0.47047f, ax, 1.0f));
  float poly = t * fmaf(t, fmaf(t, 0.7478556f, -0.0958798f), 0.3480242f);
  float er = fmaf(-poly, __expf(-ax * ax), 1.0f);
  er = copysignf(er, x);
  return 0.5f * v * (1.0f + er);
}

// ---------------- expert weight prep (verified R7-R16) ----------------
__global__ __launch_bounds__(256) void prep_weights(
    const float* __restrict__ tW1, const float* __restrict__ tW2, const float* __restrict__ tW3,
    const float* __restrict__ sW1, const float* __restrict__ sW2,
    unsigned short* __restrict__ blob)
{
  int id = blockIdx.x * 256 + threadIdx.x;
  if (id >= 6 * PER_E) return;
  int e = id / PER_E;
  int r = id - e * PER_E;
  int p = r >> 13;
  int q = r & 8191;
  int f = q >> 9;
  int l = (q >> 3) & 63;
  int j = q & 7;
  int hi = l >> 4, rl = l & 15;
  const float* src; int N, tile, ks; bool perm;
  if (p < 2)       { src = sW1 + e * 16384; N = 128; tile = 4 * p + (f >> 2);        ks = f & 3; perm = false; }
  else if (p == 2) { src = sW2 + e * 8192;  N = 64;  tile = f >> 2;                  ks = f & 3; perm = true;  }
  else if (p < 7)  { src = tW1 + e * 32768; N = 256; tile = 4 * (p - 3) + (f >> 2);  ks = f & 3; perm = false; }
  else if (p < 11) { src = tW2 + e * 65536; N = 256; tile = 2 * (p - 7) + (f >> 3);  ks = f & 7; perm = true;  }
  else if (p < 13) { src = tW3 + e * 30720; N = 120; tile = f >> 1;  ks = 2 * (p - 11) + (f & 1); perm = true; }
  else if (p < 17) { src = tW2 + e * 65536; N = 256; tile = 8 + 2 * (p - 13) + (f >> 3); ks = f & 7; perm = true; }
  else             { src = tW3 + e * 30720; N = 120; tile = f >> 1;  ks = 4 + 2 * (p - 17) + (f & 1); perm = true; }
  int k = ks * 32 + (perm ? (16 * (j >> 2) + 4 * hi + (j & 3)) : (8 * hi + j));
  int unit = tile * 16 + rl;
  blob[id] = f2bf(unit < N ? src[k * N + unit] : 0.0f);
}

// ---------------- router weight prep: 3-way bf16 split (verified R10-R16) ----------------
__global__ __launch_bounds__(256) void prep_router(
    const float* __restrict__ rW1, const float* __restrict__ rW2,
    unsigned short* __restrict__ rblob)
{
  int id = blockIdx.x * 256 + threadIdx.x;
  if (id >= RSTAGES * 8192) return;
  int p = id >> 13;
  int q = id & 8191;
  int f = q >> 9;
  int l = (q >> 3) & 63;
  int j = q & 7;
  int hi = l >> 4, rl = l & 15;
  const float* src; int N, tile, ks, part; bool perm;
  if (p < 12) { int c = p / 3; part = p % 3; src = rW1; N = 256; tile = 4 * c + (f >> 2); ks = f & 3; perm = false; }
  else        { int c = (p - 12) / 3; part = (p - 12) % 3; src = rW2; N = 128; tile = 2 * c + (f >> 3); ks = f & 7; perm = true; }
  int k = ks * 32 + (perm ? (16 * (j >> 2) + 4 * hi + (j & 3)) : (8 * hi + j));
  int unit = tile * 16 + rl;
  float v = (unit < N) ? src[k * N + unit] : 0.0f;
  unsigned short b0 = f2bf(v);
  float r1 = v - bf2f(b0);
  unsigned short b1 = f2bf(r1);
  float r2 = r1 - bf2f(b1);
  unsigned short b2 = f2bf(r2);
  rblob[id] = (part == 0) ? b0 : ((part == 1) ? b1 : b2);
}

// ---------------- shared MFMA helpers ----------------
__device__ __forceinline__ f32x4 MM16(short8v a, short8v b, f32x4 c) {
  return __builtin_amdgcn_mfma_f32_16x16x32_bf16(a, b, c, 0, 0, 0);
}
// expert: fast gelu + packed bf16 conversion
__device__ __forceinline__ void cvt16(f32x4 aE, f32x4 aO, const float* bp, int hi, short8v& fr) {
  float g[8];
  #pragma unroll
  for (int j = 0; j < 8; ++j) {
    float v = (j < 4) ? aE[j & 3] : aO[j & 3];
    int unit = 16 * (j >> 2) + 4 * hi + (j & 3);
    g[j] = geluf_fast(v + bp[unit]);
  }
  unsigned int* pr = (unsigned int*)&fr;
  pr[0] = pkbf(g[0], g[1]); pr[1] = pkbf(g[2], g[3]);
  pr[2] = pkbf(g[4], g[5]); pr[3] = pkbf(g[6], g[7]);
}
// router: precise gelu, 2-way split output
__device__ __forceinline__ void cvt16s(f32x4 aE, f32x4 aO, const float* bp, int hi,
                                       short8v& f0, short8v& f1) {
  #pragma unroll
  for (int j = 0; j < 8; ++j) {
    float v = (j < 4) ? aE[j & 3] : aO[j & 3];
    int unit = 16 * (j >> 2) + 4 * hi + (j & 3);
    float g = geluf(v + bp[unit]);
    unsigned short b0 = f2bf(g);
    f0[j] = (short)b0;
    f1[j] = (short)f2bf(g - bf2f(b0));
  }
}

// ---------------- MFMA router (verified R10-R16; 3-slot ring) ----------------
#define RFRAG(s, f) (*(const short8v*)(&wlds[((s) % 3) * 8192 + (f) * 512 + lane * 8]))

#define RSTAGE(s) do { \
    const unsigned short* gsrc_ = rblob + (s) * 8192 + w * 1024 + lane * 8; \
    unsigned short* ldst_ = &wlds[((s) % 3) * 8192 + w * 1024]; \
    _Pragma("unroll") \
    for (int i_ = 0; i_ < 2; ++i_) \
      __builtin_amdgcn_global_load_lds((gl_byte*)(gsrc_ + i_ * 512), (lds_byte*)(ldst_ + i_ * 512), 16, 0, 0); \
  } while (0)

#define RPIPE(s, nw) do { \
    asm volatile("s_waitcnt vmcnt(" #nw ")" ::: "memory"); \
    __builtin_amdgcn_sched_barrier(0); \
    __builtin_amdgcn_s_barrier(); \
    __builtin_amdgcn_sched_barrier(0); \
    if ((s) + 2 < RSTAGES) RSTAGE((s) + 2); \
  } while (0)

__global__ __launch_bounds__(512, 4) void router_mfma(
    const float* __restrict__ x, const unsigned short* __restrict__ rblob,
    const float* __restrict__ rb1, const float* __restrict__ rb2,
    const float* __restrict__ rW3, const float* __restrict__ rb3,
    float* __restrict__ probs_out,
    int* __restrict__ pairTok, float* __restrict__ pairW, int* __restrict__ pairIdx,
    int* __restrict__ cnt, float* __restrict__ probsum)
{
  __shared__ __align__(16) unsigned short wlds[3 * 8192];   // 48KB ring
  __shared__ float bLds[1160];
  __shared__ float probsLds[768];
  __shared__ float psum[8];
  __shared__ int lcnt[8], gbase[8];

  int tid = threadIdx.x;
  int lane = tid & 63;
  int w = tid >> 6;            // 8 waves
  int col = lane & 15;
  int hi = lane >> 4;
  int tok0 = blockIdx.x * 128;
  int myTok = tok0 + w * 16 + col;

  if (tid < 256) bLds[tid] = rb1[tid];
  else if (tid < 384) bLds[tid] = rb2[tid - 256];
  for (int i = tid; i < 768; i += 512) bLds[384 + i] = rW3[i];
  if (tid < 6) bLds[1152 + tid] = rb3[tid];
  if (tid < 8) { psum[tid] = 0.f; lcnt[tid] = 0; }

  short8v xf0[4], xf1[4], xf2[4];
  {
    const float* px = x + (size_t)myTok * 128 + hi * 8;
    #pragma unroll
    for (int ks = 0; ks < 4; ++ks) {
      f32x4 lo = *(const f32x4*)(px + ks * 32);
      f32x4 hv = *(const f32x4*)(px + ks * 32 + 4);
      #pragma unroll
      for (int j = 0; j < 8; ++j) {
        float v = (j < 4) ? lo[j & 3] : hv[j & 3];
        unsigned short b0 = f2bf(v);
        float r1 = v - bf2f(b0);
        unsigned short b1 = f2bf(r1);
        float r2 = r1 - bf2f(b1);
        xf0[ks][j] = (short)b0;
        xf1[ks][j] = (short)b1;
        xf2[ks][j] = (short)f2bf(r2);
      }
    }
  }
  __syncthreads();

  RSTAGE(0);
  RSTAGE(1);

  // L1: per-chunk acc -> h frags immediately (R11 fix)
  short8v h0B[8], h1B[8];
  #pragma unroll
  for (int c = 0; c < 4; ++c) {
    f32x4 acc[4] = {};
    RPIPE(3 * c, 2);
    #pragma unroll
    for (int ks = 0; ks < 4; ++ks)
      #pragma unroll
      for (int u = 0; u < 4; ++u) {
        short8v wf = RFRAG(3 * c, u * 4 + ks);
        acc[u] = MM16(wf, xf0[ks], acc[u]);
        acc[u] = MM16(wf, xf1[ks], acc[u]);
        acc[u] = MM16(wf, xf2[ks], acc[u]);
      }
    RPIPE(3 * c + 1, 2);
    #pragma unroll
    for (int ks = 0; ks < 4; ++ks)
      #pragma unroll
      for (int u = 0; u < 4; ++u) {
        short8v wf = RFRAG(3 * c + 1, u * 4 + ks);
        acc[u] = MM16(wf, xf0[ks], acc[u]);
        acc[u] = MM16(wf, xf1[ks], acc[u]);
      }
    RPIPE(3 * c + 2, 2);
    #pragma unroll
    for (int ks = 0; ks < 4; ++ks)
      #pragma unroll
      for (int u = 0; u < 4; ++u) {
        short8v wf = RFRAG(3 * c + 2, u * 4 + ks);
        acc[u] = MM16(wf, xf0[ks], acc[u]);
      }
    cvt16s(acc[0], acc[1], bLds + 32 * (2 * c),     hi, h0B[2 * c],     h1B[2 * c]);
    cvt16s(acc[2], acc[3], bLds + 32 * (2 * c + 1), hi, h0B[2 * c + 1], h1B[2 * c + 1]);
  }

  // L2
  f32x4 acc2[8] = {};
  #pragma unroll
  for (int d = 0; d < 4; ++d) {
    RPIPE(12 + 3 * d, 2);
    #pragma unroll
    for (int ks = 0; ks < 8; ++ks)
      #pragma unroll
      for (int u = 0; u < 2; ++u) {
        short8v wf = RFRAG(12 + 3 * d, u * 8 + ks);
        int t = 2 * d + u;
        acc2[t] = MM16(wf, h0B[ks], acc2[t]);
        acc2[t] = MM16(wf, h1B[ks], acc2[t]);
      }
    RPIPE(12 + 3 * d + 1, 2);
    #pragma unroll
    for (int ks = 0; ks < 8; ++ks)
      #pragma unroll
      for (int u = 0; u < 2; ++u) {
        short8v wf = RFRAG(12 + 3 * d + 1, u * 8 + ks);
        int t = 2 * d + u;
        acc2[t] = MM16(wf, h0B[ks], acc2[t]);
        acc2[t] = MM16(wf, h1B[ks], acc2[t]);
      }
    if (d < 3) { RPIPE(12 + 3 * d + 2, 2); }
    else       { RPIPE(23, 0); }
    #pragma unroll
    for (int ks = 0; ks < 8; ++ks)
      #pragma unroll
      for (int u = 0; u < 2; ++u) {
        short8v wf = RFRAG(12 + 3 * d + 2, u * 8 + ks);
        int t = 2 * d + u;
        acc2[t] = MM16(wf, h0B[ks], acc2[t]);
      }
  }

  float pl[6] = {0.f, 0.f, 0.f, 0.f, 0.f, 0.f};
  #pragma unroll
  for (int t = 0; t < 8; ++t)
    #pragma unroll
    for (int r = 0; r < 4; ++r) {
      int unit = t * 16 + 4 * hi + r;
      float h2 = geluf(acc2[t][r] + bLds[256 + unit]);
      #pragma unroll
      for (int e = 0; e < 6; ++e)
        pl[e] = fmaf(h2, bLds[384 + unit * 6 + e], pl[e]);
    }
  #pragma unroll
  for (int e = 0; e < 6; ++e) {
    pl[e] += __shfl_xor(pl[e], 16);
    pl[e] += __shfl_xor(pl[e], 32);
  }

  int i1 = 0, i2 = 0, lp1 = 0, lp2 = 0;
  float ww1 = 0.f, ww2 = 0.f;
  if (hi == 0) {
    float l0[6];
    #pragma unroll
    for (int e = 0; e < 6; ++e) l0[e] = pl[e] + bLds[1152 + e];
    float m = l0[0];
    #pragma unroll
    for (int e = 1; e < 6; ++e) m = fmaxf(m, l0[e]);
    float pe[6]; float ssum = 0.f;
    #pragma unroll
    for (int e = 0; e < 6; ++e) { pe[e] = expf(l0[e] - m); ssum += pe[e]; }
    float inv = 1.f / ssum;
    int lrow = w * 16 + col;
    #pragma unroll
    for (int e = 0; e < 6; ++e) {
      float prb = pe[e] * inv;
      probsLds[lrow * 6 + e] = prb;
      atomicAdd(&psum[e], prb);
    }
    float v1 = l0[0]; i1 = 0; float v2 = -1e30f; i2 = -1;
    #pragma unroll
    for (int e = 1; e < 6; ++e) {
      float v = l0[e];
      if (v > v1) { v2 = v1; i2 = i1; v1 = v; i1 = e; }
      else if (v > v2) { v2 = v; i2 = e; }
    }
    float e2 = expf(v2 - v1);
    float den = 1.f / (1.f + e2);
    ww1 = den; ww2 = e2 * den;
    lp1 = atomicAdd(&lcnt[i1], 1);
    lp2 = atomicAdd(&lcnt[i2], 1);
  }
  __syncthreads();
  if (tid < 6) gbase[tid] = atomicAdd(&cnt[tid], lcnt[tid]);
  __syncthreads();
  if (hi == 0) {
    int g1 = gbase[i1] + lp1, g2 = gbase[i2] + lp2;
    pairTok[i1 * N_TOK + g1] = myTok; pairW[i1 * N_TOK + g1] = ww1;
    pairTok[i2 * N_TOK + g2] = myTok; pairW[i2 * N_TOK + g2] = ww2;
    pairIdx[2 * myTok]     = i1 * N_TOK + g1;
    pairIdx[2 * myTok + 1] = i2 * N_TOK + g2;
  }
  if (tid < 6) atomicAdd(&probsum[tid], psum[tid]);
  for (int i = tid; i < 768; i += 512)
    probs_out[(size_t)tok0 * 6 + i] = probsLds[i];
}

// ---------------- aux loss + csum + active-tile list (TILE=256) ----------------
__global__ void aux_kernel(const float* __restrict__ probsum, const int* __restrict__ cnt,
                           int* __restrict__ csum, int* __restrict__ ntiles, int* __restrict__ tiles,
                           float* __restrict__ auxout)
{
  if (threadIdx.x == 0 && blockIdx.x == 0) {
    int s = 0;
    for (int e = 0; e < 6; ++e) { csum[e] = s; s += cnt[e]; }
    int nt = 0;
    for (int e = 0; e < 6; ++e)
      for (int b = 0; b < cnt[e]; b += 256)
        tiles[nt++] = (e << 16) | (b >> 8);
    ntiles[0] = nt;
    float ent = 0.f, l2 = 0.f;
    for (int e = 0; e < 6; ++e) {
      float avg = probsum[e] / (float)N_TOK;
      ent -= avg * logf(avg + 1e-8f);
      float d = avg - (1.0f / 6.0f);
      l2 += d * d;
    }
    l2 *= (1.0f / 6.0f);
    auxout[0] = -ent * 0.01f + 0.01f * l2;
  }
}

// ---------------- expert kernel: TILE=256, 8 waves, 2 token-groups/thread, 4-slot ring ----------------
#define EFRAG(s, f) (*(const short8v*)(&wlds[((s) & 3) * 8192 + (f) * 512 + lane * 8]))

// 8 waves stage 16KB: each wave 2KB (2 DMAs)
#define ESTAGE(s) do { \
    const unsigned short* gsrc_ = eblob + (s) * 8192 + w * 1024 + lane * 8; \
    unsigned short* ldst_ = &wlds[((s) & 3) * 8192 + w * 1024]; \
    _Pragma("unroll") \
    for (int i_ = 0; i_ < 2; ++i_) \
      __builtin_amdgcn_global_load_lds((gl_byte*)(gsrc_ + i_ * 512), (lds_byte*)(ldst_ + i_ * 512), 16, 0, 0); \
  } while (0)

// barrier only at even stages: drain all, issue pair (s+2,s+3)
#define EPIPE(S) do { \
    if (((S) & 1) == 0) { \
      asm volatile("s_waitcnt vmcnt(0)" ::: "memory"); \
      __builtin_amdgcn_sched_barrier(0); \
      __builtin_amdgcn_s_barrier(); \
      __builtin_amdgcn_sched_barrier(0); \
      if ((S) + 2 < NSTAGE) ESTAGE((S) + 2); \
      if ((S) + 3 < NSTAGE) ESTAGE((S) + 3); \
    } \
  } while (0)

template<int OUTMODE>   // 0 = scratch pair partials, 1 = atomicAdd into d_out
__global__ __launch_bounds__(512, 2) void expert_kernel(
    const float* __restrict__ x,
    const unsigned short* __restrict__ blob,
    const float* __restrict__ tb1, const float* __restrict__ tb2, const float* __restrict__ tb3,
    const float* __restrict__ sb1, const float* __restrict__ sb2,
    const float* __restrict__ sW3, const float* __restrict__ sb3,
    const int* __restrict__ pairTok, const float* __restrict__ pairW,
    const int* __restrict__ cnt, const int* __restrict__ csum,
    const int* __restrict__ ntiles, const int* __restrict__ tiles,
    float* __restrict__ traj_out, float* __restrict__ score_out,
    unsigned short* __restrict__ trajP, float* __restrict__ scoreP)
{
  if (blockIdx.x >= (unsigned)ntiles[0]) return;
  int ent = tiles[blockIdx.x];
  int e = ent >> 16;
  int base = (ent & 0xffff) << 8;
  int count = cnt[e];

  __shared__ __align__(16) unsigned short wlds[4 * 8192];   // 64KB 4-slot ring
  __shared__ float bLds[896];
  __shared__ int   toksLds[256];
  __shared__ float gwsLds[256];

  int tid = threadIdx.x;
  int lane = tid & 63;
  int w = tid >> 6;            // 8 waves
  int col = lane & 15;
  int hi = lane >> 4;
  const unsigned short* eblob = blob + (size_t)e * PER_E;
  int slotbase = csum[e] + base;

  if (tid < 256) {
    int idx = e * N_TOK + base + ((base + tid < count) ? tid : 0);
    toksLds[tid] = pairTok[idx];
    gwsLds[tid] = (base + tid < count) ? pairW[idx] : 0.f;
  }
  // bLds: [0,128) sb1 | [128,192) sb2 | [192,256) sW3 | [256,512) tb1 | [512,768) tb2 | [768,888) tb3
  if (tid < 128) bLds[tid] = sb1[e * 128 + tid];
  else if (tid < 192) bLds[tid] = sb2[e * 64 + tid - 128];
  else if (tid < 256) bLds[tid] = sW3[e * 64 + tid - 192];
  else bLds[tid] = tb1[e * 256 + tid - 256];
  if (tid < 256) bLds[512 + tid] = tb2[e * 256 + tid];
  if (tid < 120) bLds[768 + tid] = tb3[e * 120 + tid];
  __syncthreads();

  int row0 = w * 32 + col, row1 = row0 + 16;
  int tokA = toksLds[row0], tokB = toksLds[row1];
  bool vA = (base + row0 < count), vB = (base + row1 < count);
  float gwA = gwsLds[row0], gwB = gwsLds[row1];

  short8v xf[2][4];
  #pragma unroll
  for (int g = 0; g < 2; ++g) {
    const float* px = x + (size_t)(g ? tokB : tokA) * 128 + hi * 8;
    #pragma unroll
    for (int ks = 0; ks < 4; ++ks) {
      f32x4 lo = *(const f32x4*)(px + ks * 32);
      f32x4 hv = *(const f32x4*)(px + ks * 32 + 4);
      unsigned int* pt = (unsigned int*)&xf[g][ks];
      pt[0] = pkbf(lo[0], lo[1]); pt[1] = pkbf(lo[2], lo[3]);
      pt[2] = pkbf(hv[0], hv[1]); pt[3] = pkbf(hv[2], hv[3]);
    }
  }

  ESTAGE(0);
  ESTAGE(1);

  short8v sB[2][4];
  {
    f32x4 a[2][4] = {};
    EPIPE(0);
    #pragma unroll
    for (int f = 0; f < 16; ++f) {
      short8v wf = EFRAG(0, f);
      a[0][f >> 2] = MM16(wf, xf[0][f & 3], a[0][f >> 2]);
      a[1][f >> 2] = MM16(wf, xf[1][f & 3], a[1][f >> 2]);
    }
    cvt16(a[0][0], a[0][1], bLds + 0,  hi, sB[0][0]);  cvt16(a[0][2], a[0][3], bLds + 32, hi, sB[0][1]);
    cvt16(a[1][0], a[1][1], bLds + 0,  hi, sB[1][0]);  cvt16(a[1][2], a[1][3], bLds + 32, hi, sB[1][1]);
    f32x4 b[2][4] = {};
    EPIPE(1);
    #pragma unroll
    for (int f = 0; f < 16; ++f) {
      short8v wf = EFRAG(1, f);
      b[0][f >> 2] = MM16(wf, xf[0][f & 3], b[0][f >> 2]);
      b[1][f >> 2] = MM16(wf, xf[1][f & 3], b[1][f >> 2]);
    }
    cvt16(b[0][0], b[0][1], bLds + 64, hi, sB[0][2]);  cvt16(b[0][2], b[0][3], bLds + 96, hi, sB[0][3]);
    cvt16(b[1][0], b[1][1], bLds + 64, hi, sB[1][2]);  cvt16(b[1][2], b[1][3], bLds + 96, hi, sB[1][3]);
  }

  float pA = 0.f, pB = 0.f;
  {
    f32x4 q[2][4] = {};
    EPIPE(2);
    #pragma unroll
    for (int f = 0; f < 16; ++f) {
      short8v wf = EFRAG(2, f);
      q[0][f >> 2] = MM16(wf, sB[0][f & 3], q[0][f >> 2]);
      q[1][f >> 2] = MM16(wf, sB[1][f & 3], q[1][f >> 2]);
    }
    #pragma unroll
    for (int t = 0; t < 4; ++t)
      #pragma unroll
      for (int r = 0; r < 4; ++r) {
        int unit = t * 16 + 4 * hi + r;
        float bv = bLds[128 + unit], wv = bLds[192 + unit];
        pA += geluf_fast(q[0][t][r] + bv) * wv;
        pB += geluf_fast(q[1][t][r] + bv) * wv;
      }
    pA += __shfl_xor(pA, 16); pA += __shfl_xor(pA, 32);
    pB += __shfl_xor(pB, 16); pB += __shfl_xor(pB, 32);
  }

  short8v h1B[2][8];
  #define T1S(t, S) { \
    f32x4 a[2][4] = {}; \
    EPIPE(S); \
    _Pragma("unroll") \
    for (int f = 0; f < 16; ++f) { \
      short8v wf = EFRAG(S, f); \
      a[0][f >> 2] = MM16(wf, xf[0][f & 3], a[0][f >> 2]); \
      a[1][f >> 2] = MM16(wf, xf[1][f & 3], a[1][f >> 2]); \
    } \
    cvt16(a[0][0], a[0][1], bLds + 256 + (t) * 64,      hi, h1B[0][2 * (t)]); \
    cvt16(a[0][2], a[0][3], bLds + 256 + (t) * 64 + 32, hi, h1B[0][2 * (t) + 1]); \
    cvt16(a[1][0], a[1][1], bLds + 256 + (t) * 64,      hi, h1B[1][2 * (t)]); \
    cvt16(a[1][2], a[1][3], bLds + 256 + (t) * 64 + 32, hi, h1B[1][2 * (t) + 1]); \
  }
  T1S(0, 3) T1S(1, 4) T1S(2, 5) T1S(3, 6)

  short8v h2B[2][4];
  #define T2S(s, S, BOFF) { \
    f32x4 u[2][2] = {}; \
    EPIPE(S); \
    _Pragma("unroll") \
    for (int f = 0; f < 16; ++f) { \
      short8v wf = EFRAG(S, f); \
      u[0][f >> 3] = MM16(wf, h1B[0][f & 7], u[0][f >> 3]); \
      u[1][f >> 3] = MM16(wf, h1B[1][f & 7], u[1][f >> 3]); \
    } \
    cvt16(u[0][0], u[0][1], bLds + 512 + (BOFF) + 32 * (s), hi, h2B[0][s]); \
    cvt16(u[1][0], u[1][1], bLds + 512 + (BOFF) + 32 * (s), hi, h2B[1][s]); \
  }

  f32x4 wacc[2][8] = {};
  #define T3S(s, S) { \
    EPIPE(S); \
    _Pragma("unroll") \
    for (int f = 0; f < 16; ++f) { \
      short8v wf = EFRAG(S, f); \
      wacc[0][f >> 1] = MM16(wf, h2B[0][2 * (s) + (f & 1)], wacc[0][f >> 1]); \
      wacc[1][f >> 1] = MM16(wf, h2B[1][2 * (s) + (f & 1)], wacc[1][f >> 1]); \
    } \
  }

  T2S(0, 7, 0) T2S(1, 8, 0) T2S(2, 9, 0) T2S(3, 10, 0)
  T3S(0, 11) T3S(1, 12)
  T2S(0, 13, 128) T2S(1, 14, 128) T2S(2, 15, 128) T2S(3, 16, 128)
  T3S(0, 17) T3S(1, 18)

  if (hi == 0) {
    float sb3e = sb3[e];
    if (vA) { float v = gwA * (pA + sb3e);
      if (OUTMODE == 0) scoreP[slotbase + row0] = v; else atomicAdd(&score_out[tokA], v); }
    if (vB) { float v = gwB * (pB + sb3e);
      if (OUTMODE == 0) scoreP[slotbase + row1] = v; else atomicAdd(&score_out[tokB], v); }
  }
  #pragma unroll
  for (int g = 0; g < 2; ++g) {
    bool vv = g ? vB : vA;
    if (!vv) continue;
    float gw = g ? gwB : gwA;
    int row = g ? row1 : row0;
    int tk  = g ? tokB : tokA;
    if (OUTMODE == 0) {
      unsigned short* dst = trajP + (size_t)(slotbase + row) * 120;
      #pragma unroll
      for (int t = 0; t < 8; ++t)
        #pragma unroll
        for (int r = 0; r < 4; r += 2) {
          int unit = t * 16 + 4 * hi + r;
          if (unit + 1 < 120) {
            float a0 = gw * (wacc[g][t][r] + bLds[768 + unit]);
            float a1 = gw * (wacc[g][t][r + 1] + bLds[768 + unit + 1]);
            *(unsigned int*)(dst + unit) = pkbf(a0, a1);
          }
        }
    } else {
      float* dst = traj_out + (size_t)tk * 120;
      #pragma unroll
      for (int t = 0; t < 8; ++t)
        #pragma unroll
        for (int r = 0; r < 4; ++r) {
          int unit = t * 16 + 4 * hi + r;
          if (unit < 120) atomicAdd(&dst[unit], gw * (wacc[g][t][r] + bLds[768 + unit]));
        }
    }
  }
}

// ---------------- combine ----------------
__global__ __launch_bounds__(256) void combine_kernel(
    const int* __restrict__ pairIdx, const int* __restrict__ csum,
    const unsigned short* __restrict__ trajP, const float* __restrict__ scoreP,
    float* __restrict__ traj_out, float* __restrict__ score_out)
{
  int t = blockIdx.x * 256 + threadIdx.x;
  if (t >= N_TOK) return;
  int p0 = pairIdx[2 * t], p1 = pairIdx[2 * t + 1];
  int e0 = p0 / N_TOK, e1 = p1 / N_TOK;
  size_t s0 = (size_t)csum[e0] + (p0 - e0 * N_TOK);
  size_t s1 = (size_t)csum[e1] + (p1 - e1 * N_TOK);
  const unsigned short* r0 = trajP + s0 * 120;
  const unsigned short* r1 = trajP + s1 * 120;
  float* o = traj_out + (size_t)t * 120;
  #pragma unroll 6
  for (int i = 0; i < 30; ++i) {
    u16x4 a = *(const u16x4*)(r0 + i * 4);
    u16x4 b = *(const u16x4*)(r1 + i * 4);
    f32x4 v;
    #pragma unroll
    for (int jj = 0; jj < 4; ++jj) v[jj] = bf2f(a[jj]) + bf2f(b[jj]);
    *(f32x4*)(o + i * 4) = v;
  }
  score_out[t] = scoreP[s0] + scoreP[s1];
}

extern "C" void kernel_launch(void* const* d_in, const int* in_sizes, int n_in,
                              void* d_out, int out_size, void* d_ws, size_t ws_size,
                              hipStream_t stream) {
  (void)in_sizes; (void)n_in; (void)out_size;
  const float* x   = (const float*)d_in[0];
  const float* rW1 = (const float*)d_in[1];
  const float* rb1 = (const float*)d_in[2];
  const float* rW2 = (const float*)d_in[3];
  const float* rb2 = (const float*)d_in[4];
  const float* rW3 = (const float*)d_in[5];
  const float* rb3 = (const float*)d_in[6];
  const float* tW1 = (const float*)d_in[7];
  const float* tb1 = (const float*)d_in[8];
  const float* tW2 = (const float*)d_in[9];
  const float* tb2 = (const float*)d_in[10];
  const float* tW3 = (const float*)d_in[11];
  const float* tb3 = (const float*)d_in[12];
  const float* sW1 = (const float*)d_in[13];
  const float* sb1 = (const float*)d_in[14];
  const float* sW2 = (const float*)d_in[15];
  const float* sb2 = (const float*)d_in[16];
  const float* sW3 = (const float*)d_in[17];
  const float* sb3 = (const float*)d_in[18];
  float* out = (float*)d_out;

  // workspace carve (bytes)
  char* wsb = (char*)d_ws;
  int*   cnt     = (int*)(wsb + 0);
  float* probsum = (float*)(wsb + 32);
  int*   csum    = (int*)(wsb + 64);
  int*   ntiles  = (int*)(wsb + 96);
  int*   tiles   = (int*)(wsb + 112);
  const size_t B = 112 + 4 * ((MAXTILES + 7) & ~7);   // 112 + 3104 = 3216
  int*   pairTok = (int*)(wsb + B);
  float* pairW   = (float*)(wsb + B + (size_t)6 * N_TOK * 4);
  int*   pairIdx = (int*)(wsb + B + (size_t)12 * N_TOK * 4);
  float* scoreP  = (float*)(wsb + B + (size_t)14 * N_TOK * 4);
  unsigned short* blob  = (unsigned short*)(wsb + B + (size_t)16 * N_TOK * 4);
  unsigned short* rblob = (unsigned short*)(wsb + B + (size_t)16 * N_TOK * 4 + (size_t)6 * PER_E * 2);
  unsigned short* trajP = (unsigned short*)(wsb + B + (size_t)16 * N_TOK * 4 + (size_t)6 * PER_E * 2
                                            + (size_t)RSTAGES * 8192 * 2);
  size_t need = B + (size_t)16 * N_TOK * 4 + (size_t)6 * PER_E * 2 + (size_t)RSTAGES * 8192 * 2
              + (size_t)2 * N_TOK * 120 * 2;
  bool scratch = ws_size >= need;

  hipMemsetAsync(wsb, 0, 112, stream);
  if (!scratch) hipMemsetAsync(d_out, 0, (size_t)(N_TOK * 121) * 4, stream);

  prep_weights<<<(6 * PER_E) / 256, 256, 0, stream>>>(tW1, tW2, tW3, sW1, sW2, blob);
  prep_router<<<(RSTAGES * 8192) / 256, 256, 0, stream>>>(rW1, rW2, rblob);
  router_mfma<<<N_TOK / 128, 512, 0, stream>>>(x, rblob, rb1, rb2, rW3, rb3,
                                               out + PROB_OFF, pairTok, pairW, pairIdx, cnt, probsum);
  aux_kernel<<<1, 64, 0, stream>>>(probsum, cnt, csum, ntiles, tiles, out + AUX_OFF);
  // max tiles at TILE=256: 98304/256 + 5 partials = 389 -> 390 blocks
  if (scratch) {
    expert_kernel<0><<<390, 512, 0, stream>>>(
        x, blob, tb1, tb2, tb3, sb1, sb2, sW3, sb3, pairTok, pairW, cnt, csum, ntiles, tiles,
        out + TRAJ_OFF, out + SCORE_OFF, trajP, scoreP);
    combine_kernel<<<N_TOK / 256, 256, 0, stream>>>(pairIdx, csum, trajP, scoreP,
                                                    out + TRAJ_OFF, out + SCORE_OFF);
  } else {
    expert_kernel<1><<<390, 512, 0, stream>>>(
        x, blob, tb1, tb2, tb3, sb1, sb2, sW3, sb3, pairTok, pairW, cnt, csum, ntiles, tiles,
        out + TRAJ_OFF, out + SCORE_OFF, trajP, scoreP);
  }
}

// Round 18
// 216.611 us; speedup vs baseline: 1.1087x; 1.1087x over previous
//
#include <hip/hip_runtime.h>

#define N_TOK 49152
#define PER_E 155648      // expert blob: 19 stages * 8192 bf16 elems per expert
#define NSTAGE 19
#define RSTAGES 24        // router blob: 24 stages * 8192 bf16 elems
#define MAXTILES 774

// d_out float offsets
#define TRAJ_OFF 0
#define SCORE_OFF 5898240
#define AUX_OFF  5947392
#define PROB_OFF 5947393

typedef __attribute__((ext_vector_type(8))) short short8v;
typedef __attribute__((ext_vector_type(4))) float f32x4;
typedef __attribute__((ext_vector_type(4))) unsigned short u16x4;

typedef __attribute__((address_space(3))) unsigned char lds_byte;
typedef __attribute__((address_space(1))) const unsigned char gl_byte;

__device__ __forceinline__ unsigned short f2bf(float f) {
  unsigned int u = __float_as_uint(f);
  u = (u + 0x7FFFu + ((u >> 16) & 1u)) >> 16;
  return (unsigned short)u;
}
__device__ __forceinline__ float bf2f(unsigned short h) {
  return __uint_as_float(((unsigned int)h) << 16);
}
// pack two f32 -> 2x bf16 in one instruction
__device__ __forceinline__ unsigned int pkbf(float a, float b) {
  unsigned int r;
  asm("v_cvt_pk_bf16_f32 %0, %1, %2" : "=v"(r) : "v"(a), "v"(b));
  return r;
}
// precise erf-gelu (A&S 7.1.26, err <1.5e-7) -- ROUTER ONLY (top-2 flip safety)
__device__ __forceinline__ float geluf(float v) {
  float x = v * 0.70710678118654752f;
  float ax = fabsf(x);
  float t = __builtin_amdgcn_rcpf(fmaf(0.3275911f, ax, 1.0f));
  float p = t * fmaf(t, fmaf(t, fmaf(t, fmaf(t, 1.061405429f, -1.453152027f),
                                     1.421413741f), -0.284496736f), 0.254829592f);
  float er = 1.0f - p * __expf(-ax * ax);
  er = copysignf(er, x);
  return 0.5f * v * (1.0f + er);
}
// fast erf-gelu (A&S 7.1.25, err <2.5e-5) -- expert path
__device__ __forceinline__ float geluf_fast(float v) {
  float x = v * 0.70710678f;
  float ax = fabsf(x);
  float t = __builtin_amdgcn_rcpf(fmaf(0.47047f, ax, 1.0f));
  float poly = t * fmaf(t, fmaf(t, 0.7478556f, -0.0958798f), 0.3480242f);
  float er = fmaf(-poly, __expf(-ax * ax), 1.0f);
  er = copysignf(er, x);
  return 0.5f * v * (1.0f + er);
}

// ---------------- expert weight prep (verified R7-R17) ----------------
__global__ __launch_bounds__(256) void prep_weights(
    const float* __restrict__ tW1, const float* __restrict__ tW2, const float* __restrict__ tW3,
    const float* __restrict__ sW1, const float* __restrict__ sW2,
    unsigned short* __restrict__ blob)
{
  int id = blockIdx.x * 256 + threadIdx.x;
  if (id >= 6 * PER_E) return;
  int e = id / PER_E;
  int r = id - e * PER_E;
  int p = r >> 13;
  int q = r & 8191;
  int f = q >> 9;
  int l = (q >> 3) & 63;
  int j = q & 7;
  int hi = l >> 4, rl = l & 15;
  const float* src; int N, tile, ks; bool perm;
  if (p < 2)       { src = sW1 + e * 16384; N = 128; tile = 4 * p + (f >> 2);        ks = f & 3; perm = false; }
  else if (p == 2) { src = sW2 + e * 8192;  N = 64;  tile = f >> 2;                  ks = f & 3; perm = true;  }
  else if (p < 7)  { src = tW1 + e * 32768; N = 256; tile = 4 * (p - 3) + (f >> 2);  ks = f & 3; perm = false; }
  else if (p < 11) { src = tW2 + e * 65536; N = 256; tile = 2 * (p - 7) + (f >> 3);  ks = f & 7; perm = true;  }
  else if (p < 13) { src = tW3 + e * 30720; N = 120; tile = f >> 1;  ks = 2 * (p - 11) + (f & 1); perm = true; }
  else if (p < 17) { src = tW2 + e * 65536; N = 256; tile = 8 + 2 * (p - 13) + (f >> 3); ks = f & 7; perm = true; }
  else             { src = tW3 + e * 30720; N = 120; tile = f >> 1;  ks = 4 + 2 * (p - 17) + (f & 1); perm = true; }
  int k = ks * 32 + (perm ? (16 * (j >> 2) + 4 * hi + (j & 3)) : (8 * hi + j));
  int unit = tile * 16 + rl;
  blob[id] = f2bf(unit < N ? src[k * N + unit] : 0.0f);
}

// ---------------- router weight prep: 3-way bf16 split (verified R10-R17) ----------------
__global__ __launch_bounds__(256) void prep_router(
    const float* __restrict__ rW1, const float* __restrict__ rW2,
    unsigned short* __restrict__ rblob)
{
  int id = blockIdx.x * 256 + threadIdx.x;
  if (id >= RSTAGES * 8192) return;
  int p = id >> 13;
  int q = id & 8191;
  int f = q >> 9;
  int l = (q >> 3) & 63;
  int j = q & 7;
  int hi = l >> 4, rl = l & 15;
  const float* src; int N, tile, ks, part; bool perm;
  if (p < 12) { int c = p / 3; part = p % 3; src = rW1; N = 256; tile = 4 * c + (f >> 2); ks = f & 3; perm = false; }
  else        { int c = (p - 12) / 3; part = (p - 12) % 3; src = rW2; N = 128; tile = 2 * c + (f >> 3); ks = f & 7; perm = true; }
  int k = ks * 32 + (perm ? (16 * (j >> 2) + 4 * hi + (j & 3)) : (8 * hi + j));
  int unit = tile * 16 + rl;
  float v = (unit < N) ? src[k * N + unit] : 0.0f;
  unsigned short b0 = f2bf(v);
  float r1 = v - bf2f(b0);
  unsigned short b1 = f2bf(r1);
  float r2 = r1 - bf2f(b1);
  unsigned short b2 = f2bf(r2);
  rblob[id] = (part == 0) ? b0 : ((part == 1) ? b1 : b2);
}

// ---------------- shared MFMA helpers ----------------
__device__ __forceinline__ f32x4 MM16(short8v a, short8v b, f32x4 c) {
  return __builtin_amdgcn_mfma_f32_16x16x32_bf16(a, b, c, 0, 0, 0);
}
// expert: fast gelu + packed bf16 conversion
__device__ __forceinline__ void cvt16(f32x4 aE, f32x4 aO, const float* bp, int hi, short8v& fr) {
  float g[8];
  #pragma unroll
  for (int j = 0; j < 8; ++j) {
    float v = (j < 4) ? aE[j & 3] : aO[j & 3];
    int unit = 16 * (j >> 2) + 4 * hi + (j & 3);
    g[j] = geluf_fast(v + bp[unit]);
  }
  unsigned int* pr = (unsigned int*)&fr;
  pr[0] = pkbf(g[0], g[1]); pr[1] = pkbf(g[2], g[3]);
  pr[2] = pkbf(g[4], g[5]); pr[3] = pkbf(g[6], g[7]);
}
// router: precise gelu, 2-way split output
__device__ __forceinline__ void cvt16s(f32x4 aE, f32x4 aO, const float* bp, int hi,
                                       short8v& f0, short8v& f1) {
  #pragma unroll
  for (int j = 0; j < 8; ++j) {
    float v = (j < 4) ? aE[j & 3] : aO[j & 3];
    int unit = 16 * (j >> 2) + 4 * hi + (j & 3);
    float g = geluf(v + bp[unit]);
    unsigned short b0 = f2bf(g);
    f0[j] = (short)b0;
    f1[j] = (short)f2bf(g - bf2f(b0));
  }
}

// ---------------- MFMA router (verified R10-R17; 3-slot ring) ----------------
#define RFRAG(s, f) (*(const short8v*)(&wlds[((s) % 3) * 8192 + (f) * 512 + lane * 8]))

#define RSTAGE(s) do { \
    const unsigned short* gsrc_ = rblob + (s) * 8192 + w * 1024 + lane * 8; \
    unsigned short* ldst_ = &wlds[((s) % 3) * 8192 + w * 1024]; \
    _Pragma("unroll") \
    for (int i_ = 0; i_ < 2; ++i_) \
      __builtin_amdgcn_global_load_lds((gl_byte*)(gsrc_ + i_ * 512), (lds_byte*)(ldst_ + i_ * 512), 16, 0, 0); \
  } while (0)

#define RPIPE(s, nw) do { \
    asm volatile("s_waitcnt vmcnt(" #nw ")" ::: "memory"); \
    __builtin_amdgcn_sched_barrier(0); \
    __builtin_amdgcn_s_barrier(); \
    __builtin_amdgcn_sched_barrier(0); \
    if ((s) + 2 < RSTAGES) RSTAGE((s) + 2); \
  } while (0)

__global__ __launch_bounds__(512, 4) void router_mfma(
    const float* __restrict__ x, const unsigned short* __restrict__ rblob,
    const float* __restrict__ rb1, const float* __restrict__ rb2,
    const float* __restrict__ rW3, const float* __restrict__ rb3,
    float* __restrict__ probs_out,
    int* __restrict__ pairTok, float* __restrict__ pairW, int* __restrict__ pairIdx,
    int* __restrict__ cnt, float* __restrict__ probsum)
{
  __shared__ __align__(16) unsigned short wlds[3 * 8192];   // 48KB ring
  __shared__ float bLds[1160];
  __shared__ float probsLds[768];
  __shared__ float psum[8];
  __shared__ int lcnt[8], gbase[8];

  int tid = threadIdx.x;
  int lane = tid & 63;
  int w = tid >> 6;            // 8 waves
  int col = lane & 15;
  int hi = lane >> 4;
  int tok0 = blockIdx.x * 128;
  int myTok = tok0 + w * 16 + col;

  if (tid < 256) bLds[tid] = rb1[tid];
  else if (tid < 384) bLds[tid] = rb2[tid - 256];
  for (int i = tid; i < 768; i += 512) bLds[384 + i] = rW3[i];
  if (tid < 6) bLds[1152 + tid] = rb3[tid];
  if (tid < 8) { psum[tid] = 0.f; lcnt[tid] = 0; }

  short8v xf0[4], xf1[4], xf2[4];
  {
    const float* px = x + (size_t)myTok * 128 + hi * 8;
    #pragma unroll
    for (int ks = 0; ks < 4; ++ks) {
      f32x4 lo = *(const f32x4*)(px + ks * 32);
      f32x4 hv = *(const f32x4*)(px + ks * 32 + 4);
      #pragma unroll
      for (int j = 0; j < 8; ++j) {
        float v = (j < 4) ? lo[j & 3] : hv[j & 3];
        unsigned short b0 = f2bf(v);
        float r1 = v - bf2f(b0);
        unsigned short b1 = f2bf(r1);
        float r2 = r1 - bf2f(b1);
        xf0[ks][j] = (short)b0;
        xf1[ks][j] = (short)b1;
        xf2[ks][j] = (short)f2bf(r2);
      }
    }
  }
  __syncthreads();

  RSTAGE(0);
  RSTAGE(1);

  // L1: per-chunk acc -> h frags immediately (R11 fix)
  short8v h0B[8], h1B[8];
  #pragma unroll
  for (int c = 0; c < 4; ++c) {
    f32x4 acc[4] = {};
    RPIPE(3 * c, 2);
    #pragma unroll
    for (int ks = 0; ks < 4; ++ks)
      #pragma unroll
      for (int u = 0; u < 4; ++u) {
        short8v wf = RFRAG(3 * c, u * 4 + ks);
        acc[u] = MM16(wf, xf0[ks], acc[u]);
        acc[u] = MM16(wf, xf1[ks], acc[u]);
        acc[u] = MM16(wf, xf2[ks], acc[u]);
      }
    RPIPE(3 * c + 1, 2);
    #pragma unroll
    for (int ks = 0; ks < 4; ++ks)
      #pragma unroll
      for (int u = 0; u < 4; ++u) {
        short8v wf = RFRAG(3 * c + 1, u * 4 + ks);
        acc[u] = MM16(wf, xf0[ks], acc[u]);
        acc[u] = MM16(wf, xf1[ks], acc[u]);
      }
    RPIPE(3 * c + 2, 2);
    #pragma unroll
    for (int ks = 0; ks < 4; ++ks)
      #pragma unroll
      for (int u = 0; u < 4; ++u) {
        short8v wf = RFRAG(3 * c + 2, u * 4 + ks);
        acc[u] = MM16(wf, xf0[ks], acc[u]);
      }
    cvt16s(acc[0], acc[1], bLds + 32 * (2 * c),     hi, h0B[2 * c],     h1B[2 * c]);
    cvt16s(acc[2], acc[3], bLds + 32 * (2 * c + 1), hi, h0B[2 * c + 1], h1B[2 * c + 1]);
  }

  // L2
  f32x4 acc2[8] = {};
  #pragma unroll
  for (int d = 0; d < 4; ++d) {
    RPIPE(12 + 3 * d, 2);
    #pragma unroll
    for (int ks = 0; ks < 8; ++ks)
      #pragma unroll
      for (int u = 0; u < 2; ++u) {
        short8v wf = RFRAG(12 + 3 * d, u * 8 + ks);
        int t = 2 * d + u;
        acc2[t] = MM16(wf, h0B[ks], acc2[t]);
        acc2[t] = MM16(wf, h1B[ks], acc2[t]);
      }
    RPIPE(12 + 3 * d + 1, 2);
    #pragma unroll
    for (int ks = 0; ks < 8; ++ks)
      #pragma unroll
      for (int u = 0; u < 2; ++u) {
        short8v wf = RFRAG(12 + 3 * d + 1, u * 8 + ks);
        int t = 2 * d + u;
        acc2[t] = MM16(wf, h0B[ks], acc2[t]);
        acc2[t] = MM16(wf, h1B[ks], acc2[t]);
      }
    if (d < 3) { RPIPE(12 + 3 * d + 2, 2); }
    else       { RPIPE(23, 0); }
    #pragma unroll
    for (int ks = 0; ks < 8; ++ks)
      #pragma unroll
      for (int u = 0; u < 2; ++u) {
        short8v wf = RFRAG(12 + 3 * d + 2, u * 8 + ks);
        int t = 2 * d + u;
        acc2[t] = MM16(wf, h0B[ks], acc2[t]);
      }
  }

  float pl[6] = {0.f, 0.f, 0.f, 0.f, 0.f, 0.f};
  #pragma unroll
  for (int t = 0; t < 8; ++t)
    #pragma unroll
    for (int r = 0; r < 4; ++r) {
      int unit = t * 16 + 4 * hi + r;
      float h2 = geluf(acc2[t][r] + bLds[256 + unit]);
      #pragma unroll
      for (int e = 0; e < 6; ++e)
        pl[e] = fmaf(h2, bLds[384 + unit * 6 + e], pl[e]);
    }
  #pragma unroll
  for (int e = 0; e < 6; ++e) {
    pl[e] += __shfl_xor(pl[e], 16);
    pl[e] += __shfl_xor(pl[e], 32);
  }

  int i1 = 0, i2 = 0, lp1 = 0, lp2 = 0;
  float ww1 = 0.f, ww2 = 0.f;
  if (hi == 0) {
    float l0[6];
    #pragma unroll
    for (int e = 0; e < 6; ++e) l0[e] = pl[e] + bLds[1152 + e];
    float m = l0[0];
    #pragma unroll
    for (int e = 1; e < 6; ++e) m = fmaxf(m, l0[e]);
    float pe[6]; float ssum = 0.f;
    #pragma unroll
    for (int e = 0; e < 6; ++e) { pe[e] = expf(l0[e] - m); ssum += pe[e]; }
    float inv = 1.f / ssum;
    int lrow = w * 16 + col;
    #pragma unroll
    for (int e = 0; e < 6; ++e) {
      float prb = pe[e] * inv;
      probsLds[lrow * 6 + e] = prb;
      atomicAdd(&psum[e], prb);
    }
    float v1 = l0[0]; i1 = 0; float v2 = -1e30f; i2 = -1;
    #pragma unroll
    for (int e = 1; e < 6; ++e) {
      float v = l0[e];
      if (v > v1) { v2 = v1; i2 = i1; v1 = v; i1 = e; }
      else if (v > v2) { v2 = v; i2 = e; }
    }
    float e2 = expf(v2 - v1);
    float den = 1.f / (1.f + e2);
    ww1 = den; ww2 = e2 * den;
    lp1 = atomicAdd(&lcnt[i1], 1);
    lp2 = atomicAdd(&lcnt[i2], 1);
  }
  __syncthreads();
  if (tid < 6) gbase[tid] = atomicAdd(&cnt[tid], lcnt[tid]);
  __syncthreads();
  if (hi == 0) {
    int g1 = gbase[i1] + lp1, g2 = gbase[i2] + lp2;
    pairTok[i1 * N_TOK + g1] = myTok; pairW[i1 * N_TOK + g1] = ww1;
    pairTok[i2 * N_TOK + g2] = myTok; pairW[i2 * N_TOK + g2] = ww2;
    pairIdx[2 * myTok]     = i1 * N_TOK + g1;
    pairIdx[2 * myTok + 1] = i2 * N_TOK + g2;
  }
  if (tid < 6) atomicAdd(&probsum[tid], psum[tid]);
  for (int i = tid; i < 768; i += 512)
    probs_out[(size_t)tok0 * 6 + i] = probsLds[i];
}

// ---------------- aux loss + csum + active-tile list (TILE=512) ----------------
__global__ void aux_kernel(const float* __restrict__ probsum, const int* __restrict__ cnt,
                           int* __restrict__ csum, int* __restrict__ ntiles, int* __restrict__ tiles,
                           float* __restrict__ auxout)
{
  if (threadIdx.x == 0 && blockIdx.x == 0) {
    int s = 0;
    for (int e = 0; e < 6; ++e) { csum[e] = s; s += cnt[e]; }
    int nt = 0;
    for (int e = 0; e < 6; ++e)
      for (int b = 0; b < cnt[e]; b += 512)
        tiles[nt++] = (e << 16) | (b >> 9);
    ntiles[0] = nt;
    float ent = 0.f, l2 = 0.f;
    for (int e = 0; e < 6; ++e) {
      float avg = probsum[e] / (float)N_TOK;
      ent -= avg * logf(avg + 1e-8f);
      float d = avg - (1.0f / 6.0f);
      l2 += d * d;
    }
    l2 *= (1.0f / 6.0f);
    auxout[0] = -ent * 0.01f + 0.01f * l2;
  }
}

// ---------------- expert kernel: TILE=512, 16 waves, 2 token-groups/thread, 4-slot ring ----------------
#define EFRAG(s, f) (*(const short8v*)(&wlds[((s) & 3) * 8192 + (f) * 512 + lane * 8]))

// 16 waves stage 16KB: each wave 1KB (1 DMA)
#define ESTAGE(s) do { \
    const unsigned short* gsrc_ = eblob + (s) * 8192 + w * 512 + lane * 8; \
    unsigned short* ldst_ = &wlds[((s) & 3) * 8192 + w * 512]; \
    __builtin_amdgcn_global_load_lds((gl_byte*)gsrc_, (lds_byte*)ldst_, 16, 0, 0); \
  } while (0)

// barrier only at even stages: drain all, issue pair (s+2,s+3)
#define EPIPE(S) do { \
    if (((S) & 1) == 0) { \
      asm volatile("s_waitcnt vmcnt(0)" ::: "memory"); \
      __builtin_amdgcn_sched_barrier(0); \
      __builtin_amdgcn_s_barrier(); \
      __builtin_amdgcn_sched_barrier(0); \
      if ((S) + 2 < NSTAGE) ESTAGE((S) + 2); \
      if ((S) + 3 < NSTAGE) ESTAGE((S) + 3); \
    } \
  } while (0)

template<int OUTMODE>   // 0 = scratch pair partials, 1 = atomicAdd into d_out
__global__ __launch_bounds__(1024, 2) void expert_kernel(
    const float* __restrict__ x,
    const unsigned short* __restrict__ blob,
    const float* __restrict__ tb1, const float* __restrict__ tb2, const float* __restrict__ tb3,
    const float* __restrict__ sb1, const float* __restrict__ sb2,
    const float* __restrict__ sW3, const float* __restrict__ sb3,
    const int* __restrict__ pairTok, const float* __restrict__ pairW,
    const int* __restrict__ cnt, const int* __restrict__ csum,
    const int* __restrict__ ntiles, const int* __restrict__ tiles,
    float* __restrict__ traj_out, float* __restrict__ score_out,
    unsigned short* __restrict__ trajP, float* __restrict__ scoreP)
{
  if (blockIdx.x >= (unsigned)ntiles[0]) return;
  int ent = tiles[blockIdx.x];
  int e = ent >> 16;
  int base = (ent & 0xffff) << 9;
  int count = cnt[e];

  __shared__ __align__(16) unsigned short wlds[4 * 8192];   // 64KB 4-slot ring
  __shared__ float bLds[896];
  __shared__ int   toksLds[512];
  __shared__ float gwsLds[512];

  int tid = threadIdx.x;
  int lane = tid & 63;
  int w = tid >> 6;            // 16 waves
  int col = lane & 15;
  int hi = lane >> 4;
  const unsigned short* eblob = blob + (size_t)e * PER_E;
  int slotbase = csum[e] + base;

  if (tid < 512) {
    int idx = e * N_TOK + base + ((base + tid < count) ? tid : 0);
    toksLds[tid] = pairTok[idx];
    gwsLds[tid] = (base + tid < count) ? pairW[idx] : 0.f;
  }
  // bLds: [0,128) sb1 | [128,192) sb2 | [192,256) sW3 | [256,512) tb1 | [512,768) tb2 | [768,888) tb3
  if (tid < 128) bLds[tid] = sb1[e * 128 + tid];
  else if (tid < 192) bLds[tid] = sb2[e * 64 + tid - 128];
  else if (tid < 256) bLds[tid] = sW3[e * 64 + tid - 192];
  else if (tid < 512) bLds[tid] = tb1[e * 256 + tid - 256];
  else if (tid < 768) bLds[tid] = tb2[e * 256 + tid - 512];
  else if (tid < 888) bLds[tid] = tb3[e * 120 + tid - 768];
  __syncthreads();

  int row0 = w * 32 + col, row1 = row0 + 16;
  int tokA = toksLds[row0], tokB = toksLds[row1];
  bool vA = (base + row0 < count), vB = (base + row1 < count);
  float gwA = gwsLds[row0], gwB = gwsLds[row1];

  short8v xf[2][4];
  #pragma unroll
  for (int g = 0; g < 2; ++g) {
    const float* px = x + (size_t)(g ? tokB : tokA) * 128 + hi * 8;
    #pragma unroll
    for (int ks = 0; ks < 4; ++ks) {
      f32x4 lo = *(const f32x4*)(px + ks * 32);
      f32x4 hv = *(const f32x4*)(px + ks * 32 + 4);
      unsigned int* pt = (unsigned int*)&xf[g][ks];
      pt[0] = pkbf(lo[0], lo[1]); pt[1] = pkbf(lo[2], lo[3]);
      pt[2] = pkbf(hv[0], hv[1]); pt[3] = pkbf(hv[2], hv[3]);
    }
  }

  ESTAGE(0);
  ESTAGE(1);

  short8v sB[2][4];
  {
    f32x4 a[2][4] = {};
    EPIPE(0);
    #pragma unroll
    for (int f = 0; f < 16; ++f) {
      short8v wf = EFRAG(0, f);
      a[0][f >> 2] = MM16(wf, xf[0][f & 3], a[0][f >> 2]);
      a[1][f >> 2] = MM16(wf, xf[1][f & 3], a[1][f >> 2]);
    }
    cvt16(a[0][0], a[0][1], bLds + 0,  hi, sB[0][0]);  cvt16(a[0][2], a[0][3], bLds + 32, hi, sB[0][1]);
    cvt16(a[1][0], a[1][1], bLds + 0,  hi, sB[1][0]);  cvt16(a[1][2], a[1][3], bLds + 32, hi, sB[1][1]);
    f32x4 b[2][4] = {};
    EPIPE(1);
    #pragma unroll
    for (int f = 0; f < 16; ++f) {
      short8v wf = EFRAG(1, f);
      b[0][f >> 2] = MM16(wf, xf[0][f & 3], b[0][f >> 2]);
      b[1][f >> 2] = MM16(wf, xf[1][f & 3], b[1][f >> 2]);
    }
    cvt16(b[0][0], b[0][1], bLds + 64, hi, sB[0][2]);  cvt16(b[0][2], b[0][3], bLds + 96, hi, sB[0][3]);
    cvt16(b[1][0], b[1][1], bLds + 64, hi, sB[1][2]);  cvt16(b[1][2], b[1][3], bLds + 96, hi, sB[1][3]);
  }

  float pA = 0.f, pB = 0.f;
  {
    f32x4 q[2][4] = {};
    EPIPE(2);
    #pragma unroll
    for (int f = 0; f < 16; ++f) {
      short8v wf = EFRAG(2, f);
      q[0][f >> 2] = MM16(wf, sB[0][f & 3], q[0][f >> 2]);
      q[1][f >> 2] = MM16(wf, sB[1][f & 3], q[1][f >> 2]);
    }
    #pragma unroll
    for (int t = 0; t < 4; ++t)
      #pragma unroll
      for (int r = 0; r < 4; ++r) {
        int unit = t * 16 + 4 * hi + r;
        float bv = bLds[128 + unit], wv = bLds[192 + unit];
        pA += geluf_fast(q[0][t][r] + bv) * wv;
        pB += geluf_fast(q[1][t][r] + bv) * wv;
      }
    pA += __shfl_xor(pA, 16); pA += __shfl_xor(pA, 32);
    pB += __shfl_xor(pB, 16); pB += __shfl_xor(pB, 32);
  }

  short8v h1B[2][8];
  #define T1S(t, S) { \
    f32x4 a[2][4] = {}; \
    EPIPE(S); \
    _Pragma("unroll") \
    for (int f = 0; f < 16; ++f) { \
      short8v wf = EFRAG(S, f); \
      a[0][f >> 2] = MM16(wf, xf[0][f & 3], a[0][f >> 2]); \
      a[1][f >> 2] = MM16(wf, xf[1][f & 3], a[1][f >> 2]); \
    } \
    cvt16(a[0][0], a[0][1], bLds + 256 + (t) * 64,      hi, h1B[0][2 * (t)]); \
    cvt16(a[0][2], a[0][3], bLds + 256 + (t) * 64 + 32, hi, h1B[0][2 * (t) + 1]); \
    cvt16(a[1][0], a[1][1], bLds + 256 + (t) * 64,      hi, h1B[1][2 * (t)]); \
    cvt16(a[1][2], a[1][3], bLds + 256 + (t) * 64 + 32, hi, h1B[1][2 * (t) + 1]); \
  }
  T1S(0, 3) T1S(1, 4) T1S(2, 5) T1S(3, 6)

  short8v h2B[2][4];
  #define T2S(s, S, BOFF) { \
    f32x4 u[2][2] = {}; \
    EPIPE(S); \
    _Pragma("unroll") \
    for (int f = 0; f < 16; ++f) { \
      short8v wf = EFRAG(S, f); \
      u[0][f >> 3] = MM16(wf, h1B[0][f & 7], u[0][f >> 3]); \
      u[1][f >> 3] = MM16(wf, h1B[1][f & 7], u[1][f >> 3]); \
    } \
    cvt16(u[0][0], u[0][1], bLds + 512 + (BOFF) + 32 * (s), hi, h2B[0][s]); \
    cvt16(u[1][0], u[1][1], bLds + 512 + (BOFF) + 32 * (s), hi, h2B[1][s]); \
  }

  f32x4 wacc[2][8] = {};
  #define T3S(s, S) { \
    EPIPE(S); \
    _Pragma("unroll") \
    for (int f = 0; f < 16; ++f) { \
      short8v wf = EFRAG(S, f); \
      wacc[0][f >> 1] = MM16(wf, h2B[0][2 * (s) + (f & 1)], wacc[0][f >> 1]); \
      wacc[1][f >> 1] = MM16(wf, h2B[1][2 * (s) + (f & 1)], wacc[1][f >> 1]); \
    } \
  }

  T2S(0, 7, 0) T2S(1, 8, 0) T2S(2, 9, 0) T2S(3, 10, 0)
  T3S(0, 11) T3S(1, 12)
  T2S(0, 13, 128) T2S(1, 14, 128) T2S(2, 15, 128) T2S(3, 16, 128)
  T3S(0, 17) T3S(1, 18)

  if (hi == 0) {
    float sb3e = sb3[e];
    if (vA) { float v = gwA * (pA + sb3e);
      if (OUTMODE == 0) scoreP[slotbase + row0] = v; else atomicAdd(&score_out[tokA], v); }
    if (vB) { float v = gwB * (pB + sb3e);
      if (OUTMODE == 0) scoreP[slotbase + row1] = v; else atomicAdd(&score_out[tokB], v); }
  }
  #pragma unroll
  for (int g = 0; g < 2; ++g) {
    bool vv = g ? vB : vA;
    if (!vv) continue;
    float gw = g ? gwB : gwA;
    int row = g ? row1 : row0;
    int tk  = g ? tokB : tokA;
    if (OUTMODE == 0) {
      unsigned short* dst = trajP + (size_t)(slotbase + row) * 120;
      #pragma unroll
      for (int t = 0; t < 8; ++t)
        #pragma unroll
        for (int r = 0; r < 4; r += 2) {
          int unit = t * 16 + 4 * hi + r;
          if (unit + 1 < 120) {
            float a0 = gw * (wacc[g][t][r] + bLds[768 + unit]);
            float a1 = gw * (wacc[g][t][r + 1] + bLds[768 + unit + 1]);
            *(unsigned int*)(dst + unit) = pkbf(a0, a1);
          }
        }
    } else {
      float* dst = traj_out + (size_t)tk * 120;
      #pragma unroll
      for (int t = 0; t < 8; ++t)
        #pragma unroll
        for (int r = 0; r < 4; ++r) {
          int unit = t * 16 + 4 * hi + r;
          if (unit < 120) atomicAdd(&dst[unit], gw * (wacc[g][t][r] + bLds[768 + unit]));
        }
    }
  }
}

// ---------------- combine ----------------
__global__ __launch_bounds__(256) void combine_kernel(
    const int* __restrict__ pairIdx, const int* __restrict__ csum,
    const unsigned short* __restrict__ trajP, const float* __restrict__ scoreP,
    float* __restrict__ traj_out, float* __restrict__ score_out)
{
  int t = blockIdx.x * 256 + threadIdx.x;
  if (t >= N_TOK) return;
  int p0 = pairIdx[2 * t], p1 = pairIdx[2 * t + 1];
  int e0 = p0 / N_TOK, e1 = p1 / N_TOK;
  size_t s0 = (size_t)csum[e0] + (p0 - e0 * N_TOK);
  size_t s1 = (size_t)csum[e1] + (p1 - e1 * N_TOK);
  const unsigned short* r0 = trajP + s0 * 120;
  const unsigned short* r1 = trajP + s1 * 120;
  float* o = traj_out + (size_t)t * 120;
  #pragma unroll 6
  for (int i = 0; i < 30; ++i) {
    u16x4 a = *(const u16x4*)(r0 + i * 4);
    u16x4 b = *(const u16x4*)(r1 + i * 4);
    f32x4 v;
    #pragma unroll
    for (int jj = 0; jj < 4; ++jj) v[jj] = bf2f(a[jj]) + bf2f(b[jj]);
    *(f32x4*)(o + i * 4) = v;
  }
  score_out[t] = scoreP[s0] + scoreP[s1];
}

extern "C" void kernel_launch(void* const* d_in, const int* in_sizes, int n_in,
                              void* d_out, int out_size, void* d_ws, size_t ws_size,
                              hipStream_t stream) {
  (void)in_sizes; (void)n_in; (void)out_size;
  const float* x   = (const float*)d_in[0];
  const float* rW1 = (const float*)d_in[1];
  const float* rb1 = (const float*)d_in[2];
  const float* rW2 = (const float*)d_in[3];
  const float* rb2 = (const float*)d_in[4];
  const float* rW3 = (const float*)d_in[5];
  const float* rb3 = (const float*)d_in[6];
  const float* tW1 = (const float*)d_in[7];
  const float* tb1 = (const float*)d_in[8];
  const float* tW2 = (const float*)d_in[9];
  const float* tb2 = (const float*)d_in[10];
  const float* tW3 = (const float*)d_in[11];
  const float* tb3 = (const float*)d_in[12];
  const float* sW1 = (const float*)d_in[13];
  const float* sb1 = (const float*)d_in[14];
  const float* sW2 = (const float*)d_in[15];
  const float* sb2 = (const float*)d_in[16];
  const float* sW3 = (const float*)d_in[17];
  const float* sb3 = (const float*)d_in[18];
  float* out = (float*)d_out;

  // workspace carve (bytes)
  char* wsb = (char*)d_ws;
  int*   cnt     = (int*)(wsb + 0);
  float* probsum = (float*)(wsb + 32);
  int*   csum    = (int*)(wsb + 64);
  int*   ntiles  = (int*)(wsb + 96);
  int*   tiles   = (int*)(wsb + 112);
  const size_t B = 112 + 4 * ((MAXTILES + 7) & ~7);   // 112 + 3104 = 3216
  int*   pairTok = (int*)(wsb + B);
  float* pairW   = (float*)(wsb + B + (size_t)6 * N_TOK * 4);
  int*   pairIdx = (int*)(wsb + B + (size_t)12 * N_TOK * 4);
  float* scoreP  = (float*)(wsb + B + (size_t)14 * N_TOK * 4);
  unsigned short* blob  = (unsigned short*)(wsb + B + (size_t)16 * N_TOK * 4);
  unsigned short* rblob = (unsigned short*)(wsb + B + (size_t)16 * N_TOK * 4 + (size_t)6 * PER_E * 2);
  unsigned short* trajP = (unsigned short*)(wsb + B + (size_t)16 * N_TOK * 4 + (size_t)6 * PER_E * 2
                                            + (size_t)RSTAGES * 8192 * 2);
  size_t need = B + (size_t)16 * N_TOK * 4 + (size_t)6 * PER_E * 2 + (size_t)RSTAGES * 8192 * 2
              + (size_t)2 * N_TOK * 120 * 2;
  bool scratch = ws_size >= need;

  hipMemsetAsync(wsb, 0, 112, stream);
  if (!scratch) hipMemsetAsync(d_out, 0, (size_t)(N_TOK * 121) * 4, stream);

  prep_weights<<<(6 * PER_E) / 256, 256, 0, stream>>>(tW1, tW2, tW3, sW1, sW2, blob);
  prep_router<<<(RSTAGES * 8192) / 256, 256, 0, stream>>>(rW1, rW2, rblob);
  router_mfma<<<N_TOK / 128, 512, 0, stream>>>(x, rblob, rb1, rb2, rW3, rb3,
                                               out + PROB_OFF, pairTok, pairW, pairIdx, cnt, probsum);
  aux_kernel<<<1, 64, 0, stream>>>(probsum, cnt, csum, ntiles, tiles, out + AUX_OFF);
  // max tiles at TILE=512: 98304/512 + 5 partials = 197 -> 200 blocks
  if (scratch) {
    expert_kernel<0><<<200, 1024, 0, stream>>>(
        x, blob, tb1, tb2, tb3, sb1, sb2, sW3, sb3, pairTok, pairW, cnt, csum, ntiles, tiles,
        out + TRAJ_OFF, out + SCORE_OFF, trajP, scoreP);
    combine_kernel<<<N_TOK / 256, 256, 0, stream>>>(pairIdx, csum, trajP, scoreP,
                                                    out + TRAJ_OFF, out + SCORE_OFF);
  } else {
    expert_kernel<1><<<200, 1024, 0, stream>>>(
        x, blob, tb1, tb2, tb3, sb1, sb2, sW3, sb3, pairTok, pairW, cnt, csum, ntiles, tiles,
        out + TRAJ_OFF, out + SCORE_OFF, trajP, scoreP);
  }
}

// Round 19
// 175.585 us; speedup vs baseline: 1.3677x; 1.2337x over previous
//
#include <hip/hip_runtime.h>

#define N_TOK 49152
#define PER_E 155648      // expert blob: 19 stages * 8192 bf16 elems per expert
#define NSTAGE 19
#define RSTAGES 24        // router blob: 24 stages * 8192 bf16 elems
#define MAXTILES 774

// d_out float offsets
#define TRAJ_OFF 0
#define SCORE_OFF 5898240
#define AUX_OFF  5947392
#define PROB_OFF 5947393

typedef __attribute__((ext_vector_type(8))) short short8v;
typedef __attribute__((ext_vector_type(4))) float f32x4;
typedef __attribute__((ext_vector_type(4))) unsigned short u16x4;

typedef __attribute__((address_space(3))) unsigned char lds_byte;
typedef __attribute__((address_space(1))) const unsigned char gl_byte;

__device__ __forceinline__ unsigned short f2bf(float f) {
  unsigned int u = __float_as_uint(f);
  u = (u + 0x7FFFu + ((u >> 16) & 1u)) >> 16;
  return (unsigned short)u;
}
__device__ __forceinline__ float bf2f(unsigned short h) {
  return __uint_as_float(((unsigned int)h) << 16);
}
// pack two f32 -> 2x bf16 in one instruction
__device__ __forceinline__ unsigned int pkbf(float a, float b) {
  unsigned int r;
  asm("v_cvt_pk_bf16_f32 %0, %1, %2" : "=v"(r) : "v"(a), "v"(b));
  return r;
}
// precise erf-gelu (A&S 7.1.26, err <1.5e-7) -- ROUTER ONLY (top-2 flip safety)
__device__ __forceinline__ float geluf(float v) {
  float x = v * 0.70710678118654752f;
  float ax = fabsf(x);
  float t = __builtin_amdgcn_rcpf(fmaf(0.3275911f, ax, 1.0f));
  float p = t * fmaf(t, fmaf(t, fmaf(t, fmaf(t, 1.061405429f, -1.453152027f),
                                     1.421413741f), -0.284496736f), 0.254829592f);
  float er = 1.0f - p * __expf(-ax * ax);
  er = copysignf(er, x);
  return 0.5f * v * (1.0f + er);
}
// fast erf-gelu (A&S 7.1.25, err <2.5e-5) -- expert path
__device__ __forceinline__ float geluf_fast(float v) {
  float x = v * 0.70710678f;
  float ax = fabsf(x);
  float t = __builtin_amdgcn_rcpf(fmaf(0.47047f, ax, 1.0f));
  float poly = t * fmaf(t, fmaf(t, 0.7478556f, -0.0958798f), 0.3480242f);
  float er = fmaf(-poly, __expf(-ax * ax), 1.0f);
  er = copysignf(er, x);
  return 0.5f * v * (1.0f + er);
}

// ---------------- expert weight prep (verified R7-R18) ----------------
__global__ __launch_bounds__(256) void prep_weights(
    const float* __restrict__ tW1, const float* __restrict__ tW2, const float* __restrict__ tW3,
    const float* __restrict__ sW1, const float* __restrict__ sW2,
    unsigned short* __restrict__ blob)
{
  int id = blockIdx.x * 256 + threadIdx.x;
  if (id >= 6 * PER_E) return;
  int e = id / PER_E;
  int r = id - e * PER_E;
  int p = r >> 13;
  int q = r & 8191;
  int f = q >> 9;
  int l = (q >> 3) & 63;
  int j = q & 7;
  int hi = l >> 4, rl = l & 15;
  const float* src; int N, tile, ks; bool perm;
  if (p < 2)       { src = sW1 + e * 16384; N = 128; tile = 4 * p + (f >> 2);        ks = f & 3; perm = false; }
  else if (p == 2) { src = sW2 + e * 8192;  N = 64;  tile = f >> 2;                  ks = f & 3; perm = true;  }
  else if (p < 7)  { src = tW1 + e * 32768; N = 256; tile = 4 * (p - 3) + (f >> 2);  ks = f & 3; perm = false; }
  else if (p < 11) { src = tW2 + e * 65536; N = 256; tile = 2 * (p - 7) + (f >> 3);  ks = f & 7; perm = true;  }
  else if (p < 13) { src = tW3 + e * 30720; N = 120; tile = f >> 1;  ks = 2 * (p - 11) + (f & 1); perm = true; }
  else if (p < 17) { src = tW2 + e * 65536; N = 256; tile = 8 + 2 * (p - 13) + (f >> 3); ks = f & 7; perm = true; }
  else             { src = tW3 + e * 30720; N = 120; tile = f >> 1;  ks = 4 + 2 * (p - 17) + (f & 1); perm = true; }
  int k = ks * 32 + (perm ? (16 * (j >> 2) + 4 * hi + (j & 3)) : (8 * hi + j));
  int unit = tile * 16 + rl;
  blob[id] = f2bf(unit < N ? src[k * N + unit] : 0.0f);
}

// ---------------- router weight prep: 3-way bf16 split (verified R10-R18) ----------------
__global__ __launch_bounds__(256) void prep_router(
    const float* __restrict__ rW1, const float* __restrict__ rW2,
    unsigned short* __restrict__ rblob)
{
  int id = blockIdx.x * 256 + threadIdx.x;
  if (id >= RSTAGES * 8192) return;
  int p = id >> 13;
  int q = id & 8191;
  int f = q >> 9;
  int l = (q >> 3) & 63;
  int j = q & 7;
  int hi = l >> 4, rl = l & 15;
  const float* src; int N, tile, ks, part; bool perm;
  if (p < 12) { int c = p / 3; part = p % 3; src = rW1; N = 256; tile = 4 * c + (f >> 2); ks = f & 3; perm = false; }
  else        { int c = (p - 12) / 3; part = (p - 12) % 3; src = rW2; N = 128; tile = 2 * c + (f >> 3); ks = f & 7; perm = true; }
  int k = ks * 32 + (perm ? (16 * (j >> 2) + 4 * hi + (j & 3)) : (8 * hi + j));
  int unit = tile * 16 + rl;
  float v = (unit < N) ? src[k * N + unit] : 0.0f;
  unsigned short b0 = f2bf(v);
  float r1 = v - bf2f(b0);
  unsigned short b1 = f2bf(r1);
  float r2 = r1 - bf2f(b1);
  unsigned short b2 = f2bf(r2);
  rblob[id] = (part == 0) ? b0 : ((part == 1) ? b1 : b2);
}

// ---------------- shared MFMA helpers ----------------
__device__ __forceinline__ f32x4 MM16(short8v a, short8v b, f32x4 c) {
  return __builtin_amdgcn_mfma_f32_16x16x32_bf16(a, b, c, 0, 0, 0);
}
// expert: fast gelu + packed bf16 conversion
__device__ __forceinline__ void cvt16(f32x4 aE, f32x4 aO, const float* bp, int hi, short8v& fr) {
  float g[8];
  #pragma unroll
  for (int j = 0; j < 8; ++j) {
    float v = (j < 4) ? aE[j & 3] : aO[j & 3];
    int unit = 16 * (j >> 2) + 4 * hi + (j & 3);
    g[j] = geluf_fast(v + bp[unit]);
  }
  unsigned int* pr = (unsigned int*)&fr;
  pr[0] = pkbf(g[0], g[1]); pr[1] = pkbf(g[2], g[3]);
  pr[2] = pkbf(g[4], g[5]); pr[3] = pkbf(g[6], g[7]);
}
// router: precise gelu, 2-way split output
__device__ __forceinline__ void cvt16s(f32x4 aE, f32x4 aO, const float* bp, int hi,
                                       short8v& f0, short8v& f1) {
  #pragma unroll
  for (int j = 0; j < 8; ++j) {
    float v = (j < 4) ? aE[j & 3] : aO[j & 3];
    int unit = 16 * (j >> 2) + 4 * hi + (j & 3);
    float g = geluf(v + bp[unit]);
    unsigned short b0 = f2bf(g);
    f0[j] = (short)b0;
    f1[j] = (short)f2bf(g - bf2f(b0));
  }
}

// ---------------- MFMA router (verified R10-R18; 3-slot ring) ----------------
#define RFRAG(s, f) (*(const short8v*)(&wlds[((s) % 3) * 8192 + (f) * 512 + lane * 8]))

#define RSTAGE(s) do { \
    const unsigned short* gsrc_ = rblob + (s) * 8192 + w * 1024 + lane * 8; \
    unsigned short* ldst_ = &wlds[((s) % 3) * 8192 + w * 1024]; \
    _Pragma("unroll") \
    for (int i_ = 0; i_ < 2; ++i_) \
      __builtin_amdgcn_global_load_lds((gl_byte*)(gsrc_ + i_ * 512), (lds_byte*)(ldst_ + i_ * 512), 16, 0, 0); \
  } while (0)

#define RPIPE(s, nw) do { \
    asm volatile("s_waitcnt vmcnt(" #nw ")" ::: "memory"); \
    __builtin_amdgcn_sched_barrier(0); \
    __builtin_amdgcn_s_barrier(); \
    __builtin_amdgcn_sched_barrier(0); \
    if ((s) + 2 < RSTAGES) RSTAGE((s) + 2); \
  } while (0)

__global__ __launch_bounds__(512, 4) void router_mfma(
    const float* __restrict__ x, const unsigned short* __restrict__ rblob,
    const float* __restrict__ rb1, const float* __restrict__ rb2,
    const float* __restrict__ rW3, const float* __restrict__ rb3,
    float* __restrict__ probs_out,
    int* __restrict__ pairTok, float* __restrict__ pairW, int* __restrict__ pairIdx,
    int* __restrict__ cnt, float* __restrict__ probsum)
{
  __shared__ __align__(16) unsigned short wlds[3 * 8192];   // 48KB ring
  __shared__ float bLds[1160];
  __shared__ float probsLds[768];
  __shared__ float psum[8];
  __shared__ int lcnt[8], gbase[8];

  int tid = threadIdx.x;
  int lane = tid & 63;
  int w = tid >> 6;            // 8 waves
  int col = lane & 15;
  int hi = lane >> 4;
  int tok0 = blockIdx.x * 128;
  int myTok = tok0 + w * 16 + col;

  if (tid < 256) bLds[tid] = rb1[tid];
  else if (tid < 384) bLds[tid] = rb2[tid - 256];
  for (int i = tid; i < 768; i += 512) bLds[384 + i] = rW3[i];
  if (tid < 6) bLds[1152 + tid] = rb3[tid];
  if (tid < 8) { psum[tid] = 0.f; lcnt[tid] = 0; }

  short8v xf0[4], xf1[4], xf2[4];
  {
    const float* px = x + (size_t)myTok * 128 + hi * 8;
    #pragma unroll
    for (int ks = 0; ks < 4; ++ks) {
      f32x4 lo = *(const f32x4*)(px + ks * 32);
      f32x4 hv = *(const f32x4*)(px + ks * 32 + 4);
      #pragma unroll
      for (int j = 0; j < 8; ++j) {
        float v = (j < 4) ? lo[j & 3] : hv[j & 3];
        unsigned short b0 = f2bf(v);
        float r1 = v - bf2f(b0);
        unsigned short b1 = f2bf(r1);
        float r2 = r1 - bf2f(b1);
        xf0[ks][j] = (short)b0;
        xf1[ks][j] = (short)b1;
        xf2[ks][j] = (short)f2bf(r2);
      }
    }
  }
  __syncthreads();

  RSTAGE(0);
  RSTAGE(1);

  // L1: per-chunk acc -> h frags immediately (R11 fix)
  short8v h0B[8], h1B[8];
  #pragma unroll
  for (int c = 0; c < 4; ++c) {
    f32x4 acc[4] = {};
    RPIPE(3 * c, 2);
    #pragma unroll
    for (int ks = 0; ks < 4; ++ks)
      #pragma unroll
      for (int u = 0; u < 4; ++u) {
        short8v wf = RFRAG(3 * c, u * 4 + ks);
        acc[u] = MM16(wf, xf0[ks], acc[u]);
        acc[u] = MM16(wf, xf1[ks], acc[u]);
        acc[u] = MM16(wf, xf2[ks], acc[u]);
      }
    RPIPE(3 * c + 1, 2);
    #pragma unroll
    for (int ks = 0; ks < 4; ++ks)
      #pragma unroll
      for (int u = 0; u < 4; ++u) {
        short8v wf = RFRAG(3 * c + 1, u * 4 + ks);
        acc[u] = MM16(wf, xf0[ks], acc[u]);
        acc[u] = MM16(wf, xf1[ks], acc[u]);
      }
    RPIPE(3 * c + 2, 2);
    #pragma unroll
    for (int ks = 0; ks < 4; ++ks)
      #pragma unroll
      for (int u = 0; u < 4; ++u) {
        short8v wf = RFRAG(3 * c + 2, u * 4 + ks);
        acc[u] = MM16(wf, xf0[ks], acc[u]);
      }
    cvt16s(acc[0], acc[1], bLds + 32 * (2 * c),     hi, h0B[2 * c],     h1B[2 * c]);
    cvt16s(acc[2], acc[3], bLds + 32 * (2 * c + 1), hi, h0B[2 * c + 1], h1B[2 * c + 1]);
  }

  // L2
  f32x4 acc2[8] = {};
  #pragma unroll
  for (int d = 0; d < 4; ++d) {
    RPIPE(12 + 3 * d, 2);
    #pragma unroll
    for (int ks = 0; ks < 8; ++ks)
      #pragma unroll
      for (int u = 0; u < 2; ++u) {
        short8v wf = RFRAG(12 + 3 * d, u * 8 + ks);
        int t = 2 * d + u;
        acc2[t] = MM16(wf, h0B[ks], acc2[t]);
        acc2[t] = MM16(wf, h1B[ks], acc2[t]);
      }
    RPIPE(12 + 3 * d + 1, 2);
    #pragma unroll
    for (int ks = 0; ks < 8; ++ks)
      #pragma unroll
      for (int u = 0; u < 2; ++u) {
        short8v wf = RFRAG(12 + 3 * d + 1, u * 8 + ks);
        int t = 2 * d + u;
        acc2[t] = MM16(wf, h0B[ks], acc2[t]);
        acc2[t] = MM16(wf, h1B[ks], acc2[t]);
      }
    if (d < 3) { RPIPE(12 + 3 * d + 2, 2); }
    else       { RPIPE(23, 0); }
    #pragma unroll
    for (int ks = 0; ks < 8; ++ks)
      #pragma unroll
      for (int u = 0; u < 2; ++u) {
        short8v wf = RFRAG(12 + 3 * d + 2, u * 8 + ks);
        int t = 2 * d + u;
        acc2[t] = MM16(wf, h0B[ks], acc2[t]);
      }
  }

  float pl[6] = {0.f, 0.f, 0.f, 0.f, 0.f, 0.f};
  #pragma unroll
  for (int t = 0; t < 8; ++t)
    #pragma unroll
    for (int r = 0; r < 4; ++r) {
      int unit = t * 16 + 4 * hi + r;
      float h2 = geluf(acc2[t][r] + bLds[256 + unit]);
      #pragma unroll
      for (int e = 0; e < 6; ++e)
        pl[e] = fmaf(h2, bLds[384 + unit * 6 + e], pl[e]);
    }
  #pragma unroll
  for (int e = 0; e < 6; ++e) {
    pl[e] += __shfl_xor(pl[e], 16);
    pl[e] += __shfl_xor(pl[e], 32);
  }

  int i1 = 0, i2 = 0, lp1 = 0, lp2 = 0;
  float ww1 = 0.f, ww2 = 0.f;
  if (hi == 0) {
    float l0[6];
    #pragma unroll
    for (int e = 0; e < 6; ++e) l0[e] = pl[e] + bLds[1152 + e];
    float m = l0[0];
    #pragma unroll
    for (int e = 1; e < 6; ++e) m = fmaxf(m, l0[e]);
    float pe[6]; float ssum = 0.f;
    #pragma unroll
    for (int e = 0; e < 6; ++e) { pe[e] = expf(l0[e] - m); ssum += pe[e]; }
    float inv = 1.f / ssum;
    int lrow = w * 16 + col;
    #pragma unroll
    for (int e = 0; e < 6; ++e) {
      float prb = pe[e] * inv;
      probsLds[lrow * 6 + e] = prb;
      atomicAdd(&psum[e], prb);
    }
    float v1 = l0[0]; i1 = 0; float v2 = -1e30f; i2 = -1;
    #pragma unroll
    for (int e = 1; e < 6; ++e) {
      float v = l0[e];
      if (v > v1) { v2 = v1; i2 = i1; v1 = v; i1 = e; }
      else if (v > v2) { v2 = v; i2 = e; }
    }
    float e2 = expf(v2 - v1);
    float den = 1.f / (1.f + e2);
    ww1 = den; ww2 = e2 * den;
    lp1 = atomicAdd(&lcnt[i1], 1);
    lp2 = atomicAdd(&lcnt[i2], 1);
  }
  __syncthreads();
  if (tid < 6) gbase[tid] = atomicAdd(&cnt[tid], lcnt[tid]);
  __syncthreads();
  if (hi == 0) {
    int g1 = gbase[i1] + lp1, g2 = gbase[i2] + lp2;
    pairTok[i1 * N_TOK + g1] = myTok; pairW[i1 * N_TOK + g1] = ww1;
    pairTok[i2 * N_TOK + g2] = myTok; pairW[i2 * N_TOK + g2] = ww2;
    pairIdx[2 * myTok]     = i1 * N_TOK + g1;
    pairIdx[2 * myTok + 1] = i2 * N_TOK + g2;
  }
  if (tid < 6) atomicAdd(&probsum[tid], psum[tid]);
  for (int i = tid; i < 768; i += 512)
    probs_out[(size_t)tok0 * 6 + i] = probsLds[i];
}

// ---------------- aux loss + csum + active-tile list (TILE=256) ----------------
__global__ void aux_kernel(const float* __restrict__ probsum, const int* __restrict__ cnt,
                           int* __restrict__ csum, int* __restrict__ ntiles, int* __restrict__ tiles,
                           float* __restrict__ auxout)
{
  if (threadIdx.x == 0 && blockIdx.x == 0) {
    int s = 0;
    for (int e = 0; e < 6; ++e) { csum[e] = s; s += cnt[e]; }
    int nt = 0;
    for (int e = 0; e < 6; ++e)
      for (int b = 0; b < cnt[e]; b += 256)
        tiles[nt++] = (e << 16) | (b >> 8);
    ntiles[0] = nt;
    float ent = 0.f, l2 = 0.f;
    for (int e = 0; e < 6; ++e) {
      float avg = probsum[e] / (float)N_TOK;
      ent -= avg * logf(avg + 1e-8f);
      float d = avg - (1.0f / 6.0f);
      l2 += d * d;
    }
    l2 *= (1.0f / 6.0f);
    auxout[0] = -ent * 0.01f + 0.01f * l2;
  }
}

// ---------------- expert kernel: TILE=256, 16 waves, 4-slot ring, barrier every 2 stages (R16 best) ----------------
#define EFRAG(s, f) (*(const short8v*)(&wlds[((s) & 3) * 8192 + (f) * 512 + lane * 8]))

// each of 16 waves stages 1KB of the 16KB stage (one DMA)
#define ESTAGE(s) do { \
    const unsigned short* gsrc_ = eblob + (s) * 8192 + w * 512 + lane * 8; \
    unsigned short* ldst_ = &wlds[((s) & 3) * 8192 + w * 512]; \
    __builtin_amdgcn_global_load_lds((gl_byte*)gsrc_, (lds_byte*)ldst_, 16, 0, 0); \
  } while (0)

// barrier only at even stages: drain pair (s,s+1), issue pair (s+2,s+3)
#define EPIPE(S) do { \
    if (((S) & 1) == 0) { \
      asm volatile("s_waitcnt vmcnt(0)" ::: "memory"); \
      __builtin_amdgcn_sched_barrier(0); \
      __builtin_amdgcn_s_barrier(); \
      __builtin_amdgcn_sched_barrier(0); \
      if ((S) + 2 < NSTAGE) ESTAGE((S) + 2); \
      if ((S) + 3 < NSTAGE) ESTAGE((S) + 3); \
    } \
  } while (0)

template<int OUTMODE>   // 0 = scratch pair partials, 1 = atomicAdd into d_out
__global__ __launch_bounds__(1024, 4) void expert_kernel(
    const float* __restrict__ x,
    const unsigned short* __restrict__ blob,
    const float* __restrict__ tb1, const float* __restrict__ tb2, const float* __restrict__ tb3,
    const float* __restrict__ sb1, const float* __restrict__ sb2,
    const float* __restrict__ sW3, const float* __restrict__ sb3,
    const int* __restrict__ pairTok, const float* __restrict__ pairW,
    const int* __restrict__ cnt, const int* __restrict__ csum,
    const int* __restrict__ ntiles, const int* __restrict__ tiles,
    float* __restrict__ traj_out, float* __restrict__ score_out,
    unsigned short* __restrict__ trajP, float* __restrict__ scoreP)
{
  if (blockIdx.x >= (unsigned)ntiles[0]) return;
  int ent = tiles[blockIdx.x];
  int e = ent >> 16;
  int base = (ent & 0xffff) << 8;
  int count = cnt[e];

  __shared__ __align__(16) unsigned short wlds[4 * 8192];   // 64KB 4-slot ring
  __shared__ float bLds[896];
  __shared__ int   toksLds[256];
  __shared__ float gwsLds[256];

  int tid = threadIdx.x;
  int lane = tid & 63;
  int w = tid >> 6;            // 16 waves
  int col = lane & 15;
  int hi = lane >> 4;
  const unsigned short* eblob = blob + (size_t)e * PER_E;
  int slotbase = csum[e] + base;

  if (tid < 256) {
    int idx = e * N_TOK + base + ((base + tid < count) ? tid : 0);
    toksLds[tid] = pairTok[idx];
    gwsLds[tid] = (base + tid < count) ? pairW[idx] : 0.f;
  }
  // bLds layout: [0,128) sb1 | [128,192) sb2 | [192,256) sW3 | [256,512) tb1 | [512,768) tb2 | [768,888) tb3
  if (tid < 128) bLds[tid] = sb1[e * 128 + tid];
  else if (tid < 192) bLds[tid] = sb2[e * 64 + tid - 128];
  else if (tid < 256) bLds[tid] = sW3[e * 64 + tid - 192];
  else if (tid < 512) bLds[tid] = tb1[e * 256 + tid - 256];
  else if (tid < 768) bLds[tid] = tb2[e * 256 + tid - 512];
  else if (tid < 888) bLds[tid] = tb3[e * 120 + tid - 768];
  __syncthreads();

  int row = w * 16 + col;
  int tok = toksLds[row];
  bool valid = (base + row < count);
  float gw = gwsLds[row];

  short8v xf[4];
  {
    const float* px = x + (size_t)tok * 128 + hi * 8;
    #pragma unroll
    for (int ks = 0; ks < 4; ++ks) {
      f32x4 lo = *(const f32x4*)(px + ks * 32);
      f32x4 hv = *(const f32x4*)(px + ks * 32 + 4);
      unsigned int* pt = (unsigned int*)&xf[ks];
      pt[0] = pkbf(lo[0], lo[1]); pt[1] = pkbf(lo[2], lo[3]);
      pt[2] = pkbf(hv[0], hv[1]); pt[3] = pkbf(hv[2], hv[3]);
    }
  }

  ESTAGE(0);
  ESTAGE(1);

  short8v sB[4];
  {
    f32x4 a[4] = {};
    EPIPE(0);
    #pragma unroll
    for (int f = 0; f < 16; ++f)
      a[f >> 2] = MM16(EFRAG(0, f), xf[f & 3], a[f >> 2]);
    cvt16(a[0], a[1], bLds + 0,  hi, sB[0]);  cvt16(a[2], a[3], bLds + 32, hi, sB[1]);
    f32x4 b[4] = {};
    EPIPE(1);
    #pragma unroll
    for (int f = 0; f < 16; ++f)
      b[f >> 2] = MM16(EFRAG(1, f), xf[f & 3], b[f >> 2]);
    cvt16(b[0], b[1], bLds + 64, hi, sB[2]);  cvt16(b[2], b[3], bLds + 96, hi, sB[3]);
  }

  float p0 = 0.f;
  {
    f32x4 q[4] = {};
    EPIPE(2);
    #pragma unroll
    for (int f = 0; f < 16; ++f)
      q[f >> 2] = MM16(EFRAG(2, f), sB[f & 3], q[f >> 2]);
    #pragma unroll
    for (int t = 0; t < 4; ++t)
      #pragma unroll
      for (int r = 0; r < 4; ++r) {
        int unit = t * 16 + 4 * hi + r;
        p0 += geluf_fast(q[t][r] + bLds[128 + unit]) * bLds[192 + unit];
      }
    p0 += __shfl_xor(p0, 16); p0 += __shfl_xor(p0, 32);
  }

  short8v h1B[8];
  #define T1S(t, S) { \
    f32x4 a[4] = {}; \
    EPIPE(S); \
    _Pragma("unroll") \
    for (int f = 0; f < 16; ++f) \
      a[f >> 2] = MM16(EFRAG(S, f), xf[f & 3], a[f >> 2]); \
    cvt16(a[0], a[1], bLds + 256 + (t) * 64,      hi, h1B[2 * (t)]); \
    cvt16(a[2], a[3], bLds + 256 + (t) * 64 + 32, hi, h1B[2 * (t) + 1]); \
  }
  T1S(0, 3) T1S(1, 4) T1S(2, 5) T1S(3, 6)

  short8v h2B[4];
  #define T2S(s, S, BOFF) { \
    f32x4 u[2] = {}; \
    EPIPE(S); \
    _Pragma("unroll") \
    for (int f = 0; f < 16; ++f) \
      u[f >> 3] = MM16(EFRAG(S, f), h1B[f & 7], u[f >> 3]); \
    cvt16(u[0], u[1], bLds + 512 + (BOFF) + 32 * (s), hi, h2B[s]); \
  }

  f32x4 wacc[8] = {};
  #define T3S(s, S) { \
    EPIPE(S); \
    _Pragma("unroll") \
    for (int f = 0; f < 16; ++f) \
      wacc[f >> 1] = MM16(EFRAG(S, f), h2B[2 * (s) + (f & 1)], wacc[f >> 1]); \
  }

  T2S(0, 7, 0) T2S(1, 8, 0) T2S(2, 9, 0) T2S(3, 10, 0)
  T3S(0, 11) T3S(1, 12)
  T2S(0, 13, 128) T2S(1, 14, 128) T2S(2, 15, 128) T2S(3, 16, 128)
  T3S(0, 17) T3S(1, 18)

  if (hi == 0 && valid) {
    float v = gw * (p0 + sb3[e]);
    if (OUTMODE == 0) scoreP[slotbase + row] = v; else atomicAdd(&score_out[tok], v);
  }
  if (valid) {
    if (OUTMODE == 0) {
      unsigned short* dst = trajP + (size_t)(slotbase + row) * 120;
      #pragma unroll
      for (int t = 0; t < 8; ++t)
        #pragma unroll
        for (int r = 0; r < 4; r += 2) {
          int unit = t * 16 + 4 * hi + r;
          if (unit + 1 < 120) {
            float a0 = gw * (wacc[t][r] + bLds[768 + unit]);
            float a1 = gw * (wacc[t][r + 1] + bLds[768 + unit + 1]);
            *(unsigned int*)(dst + unit) = pkbf(a0, a1);
          }
        }
    } else {
      float* dst = traj_out + (size_t)tok * 120;
      #pragma unroll
      for (int t = 0; t < 8; ++t)
        #pragma unroll
        for (int r = 0; r < 4; ++r) {
          int unit = t * 16 + 4 * hi + r;
          if (unit < 120) atomicAdd(&dst[unit], gw * (wacc[t][r] + bLds[768 + unit]));
        }
    }
  }
}

// ---------------- combine ----------------
__global__ __launch_bounds__(256) void combine_kernel(
    const int* __restrict__ pairIdx, const int* __restrict__ csum,
    const unsigned short* __restrict__ trajP, const float* __restrict__ scoreP,
    float* __restrict__ traj_out, float* __restrict__ score_out)
{
  int t = blockIdx.x * 256 + threadIdx.x;
  if (t >= N_TOK) return;
  int p0 = pairIdx[2 * t], p1 = pairIdx[2 * t + 1];
  int e0 = p0 / N_TOK, e1 = p1 / N_TOK;
  size_t s0 = (size_t)csum[e0] + (p0 - e0 * N_TOK);
  size_t s1 = (size_t)csum[e1] + (p1 - e1 * N_TOK);
  const unsigned short* r0 = trajP + s0 * 120;
  const unsigned short* r1 = trajP + s1 * 120;
  float* o = traj_out + (size_t)t * 120;
  #pragma unroll 6
  for (int i = 0; i < 30; ++i) {
    u16x4 a = *(const u16x4*)(r0 + i * 4);
    u16x4 b = *(const u16x4*)(r1 + i * 4);
    f32x4 v;
    #pragma unroll
    for (int jj = 0; jj < 4; ++jj) v[jj] = bf2f(a[jj]) + bf2f(b[jj]);
    *(f32x4*)(o + i * 4) = v;
  }
  score_out[t] = scoreP[s0] + scoreP[s1];
}

extern "C" void kernel_launch(void* const* d_in, const int* in_sizes, int n_in,
                              void* d_out, int out_size, void* d_ws, size_t ws_size,
                              hipStream_t stream) {
  (void)in_sizes; (void)n_in; (void)out_size;
  const float* x   = (const float*)d_in[0];
  const float* rW1 = (const float*)d_in[1];
  const float* rb1 = (const float*)d_in[2];
  const float* rW2 = (const float*)d_in[3];
  const float* rb2 = (const float*)d_in[4];
  const float* rW3 = (const float*)d_in[5];
  const float* rb3 = (const float*)d_in[6];
  const float* tW1 = (const float*)d_in[7];
  const float* tb1 = (const float*)d_in[8];
  const float* tW2 = (const float*)d_in[9];
  const float* tb2 = (const float*)d_in[10];
  const float* tW3 = (const float*)d_in[11];
  const float* tb3 = (const float*)d_in[12];
  const float* sW1 = (const float*)d_in[13];
  const float* sb1 = (const float*)d_in[14];
  const float* sW2 = (const float*)d_in[15];
  const float* sb2 = (const float*)d_in[16];
  const float* sW3 = (const float*)d_in[17];
  const float* sb3 = (const float*)d_in[18];
  float* out = (float*)d_out;

  // workspace carve (bytes)
  char* wsb = (char*)d_ws;
  int*   cnt     = (int*)(wsb + 0);
  float* probsum = (float*)(wsb + 32);
  int*   csum    = (int*)(wsb + 64);
  int*   ntiles  = (int*)(wsb + 96);
  int*   tiles   = (int*)(wsb + 112);
  const size_t B = 112 + 4 * ((MAXTILES + 7) & ~7);   // 112 + 3104 = 3216
  int*   pairTok = (int*)(wsb + B);
  float* pairW   = (float*)(wsb + B + (size_t)6 * N_TOK * 4);
  int*   pairIdx = (int*)(wsb + B + (size_t)12 * N_TOK * 4);
  float* scoreP  = (float*)(wsb + B + (size_t)14 * N_TOK * 4);
  unsigned short* blob  = (unsigned short*)(wsb + B + (size_t)16 * N_TOK * 4);
  unsigned short* rblob = (unsigned short*)(wsb + B + (size_t)16 * N_TOK * 4 + (size_t)6 * PER_E * 2);
  unsigned short* trajP = (unsigned short*)(wsb + B + (size_t)16 * N_TOK * 4 + (size_t)6 * PER_E * 2
                                            + (size_t)RSTAGES * 8192 * 2);
  size_t need = B + (size_t)16 * N_TOK * 4 + (size_t)6 * PER_E * 2 + (size_t)RSTAGES * 8192 * 2
              + (size_t)2 * N_TOK * 120 * 2;
  bool scratch = ws_size >= need;

  hipMemsetAsync(wsb, 0, 112, stream);
  if (!scratch) hipMemsetAsync(d_out, 0, (size_t)(N_TOK * 121) * 4, stream);

  prep_weights<<<(6 * PER_E) / 256, 256, 0, stream>>>(tW1, tW2, tW3, sW1, sW2, blob);
  prep_router<<<(RSTAGES * 8192) / 256, 256, 0, stream>>>(rW1, rW2, rblob);
  router_mfma<<<N_TOK / 128, 512, 0, stream>>>(x, rblob, rb1, rb2, rW3, rb3,
                                               out + PROB_OFF, pairTok, pairW, pairIdx, cnt, probsum);
  aux_kernel<<<1, 64, 0, stream>>>(probsum, cnt, csum, ntiles, tiles, out + AUX_OFF);
  // max tiles at TILE=256: 98304/256 + 5 partials = 389 -> 390 blocks
  if (scratch) {
    expert_kernel<0><<<390, 1024, 0, stream>>>(
        x, blob, tb1, tb2, tb3, sb1, sb2, sW3, sb3, pairTok, pairW, cnt, csum, ntiles, tiles,
        out + TRAJ_OFF, out + SCORE_OFF, trajP, scoreP);
    combine_kernel<<<N_TOK / 256, 256, 0, stream>>>(pairIdx, csum, trajP, scoreP,
                                                    out + TRAJ_OFF, out + SCORE_OFF);
  } else {
    expert_kernel<1><<<390, 1024, 0, stream>>>(
        x, blob, tb1, tb2, tb3, sb1, sb2, sW3, sb3, pairTok, pairW, cnt, csum, ntiles, tiles,
        out + TRAJ_OFF, out + SCORE_OFF, trajP, scoreP);
  }
}